// Round 8
// baseline (1228.129 us; speedup 1.0000x reference)
//
#include <hip/hip_runtime.h>
#include <hip/hip_bf16.h>

#define ND 50000
#define NS 30000
#define NE 1000000
#define EL 200000
#define NTOT (NS + ND)          // 80000
#define SCAN_BLK ((NTOT + 1023) / 1024)   // 79
#define NCHUNK 8                // feature chunks of 32 feats (64 B) == queues == XCDs
#define NGRP (NTOT / 32)        // 2500 node-groups of 32 (exact)

typedef short short8 __attribute__((ext_vector_type(8)));
typedef float f32x4 __attribute__((ext_vector_type(4)));

__device__ __forceinline__ float b2f(unsigned short u) {
    union { unsigned int i; float f; } c; c.i = ((unsigned int)u) << 16; return c.f;
}
__device__ __forceinline__ unsigned short f2b(float f) {
    __hip_bfloat16 h = __float2bfloat16(f);   // RNE
    union { __hip_bfloat16 h; unsigned short u; } c; c.h = h; return c.u;
}

// async global->LDS, 16 B per lane; LDS dest is wave-uniform base + lane*16
__device__ __forceinline__ void gload_lds16(const unsigned short* g, unsigned short* l) {
    __builtin_amdgcn_global_load_lds(
        (const __attribute__((address_space(1))) unsigned int*)g,
        (__attribute__((address_space(3))) unsigned int*)l, 16, 0, 0);
}

// ---------------- CSR build ----------------

__global__ void zero_kernel(int* a, int n) {
    int i = blockIdx.x * blockDim.x + threadIdx.x;
    if (i < n) a[i] = 0;
}

// histogram + per-edge rank in one pass (atomic return IS the rank)
__global__ void rank_kernel(const int* __restrict__ src, const int* __restrict__ dst,
                            int* cnt_drug, int* cnt_dis,
                            unsigned short* __restrict__ rank_sd,
                            unsigned short* __restrict__ rank_ds, int n) {
    int i = blockIdx.x * blockDim.x + threadIdx.x;
    if (i < n) {
        int s = src[i], d = dst[i];
        rank_ds[i] = (unsigned short)atomicAdd(&cnt_dis[d], 1);
        rank_sd[i] = (unsigned short)atomicAdd(&cnt_drug[s], 1);
    }
}

// hierarchical scan over concatenated [cnt_dis | cnt_drug] (NTOT ints)
__global__ __launch_bounds__(256) void scan_part(const int* __restrict__ cnt,
                                                 int* __restrict__ bsum) {
    __shared__ int red[4];
    int t = threadIdx.x, lane = t & 63, wid = t >> 6;
    int base = blockIdx.x * 1024 + t * 4;
    int s = 0;
    if (base < NTOT) {           // NTOT % 4 == 0 -> whole int4 in bounds
        int4 c = *reinterpret_cast<const int4*>(cnt + base);
        s = c.x + c.y + c.z + c.w;
    }
#pragma unroll
    for (int off = 32; off; off >>= 1) s += __shfl_down(s, off);
    if (lane == 0) red[wid] = s;
    __syncthreads();
    if (t == 0) bsum[blockIdx.x] = red[0] + red[1] + red[2] + red[3];
}

__global__ void scan_top(int* bsum, int nb) {   // 1 block x 64 threads, nb <= 128
    int lane = threadIdx.x;
    int a0 = lane < nb ? bsum[lane] : 0;
    int a1 = (64 + lane) < nb ? bsum[64 + lane] : 0;
    int i0 = a0, i1 = a1;
#pragma unroll
    for (int off = 1; off < 64; off <<= 1) {
        int t0 = __shfl_up(i0, off);
        int t1 = __shfl_up(i1, off);
        if (lane >= off) { i0 += t0; i1 += t1; }
    }
    int tot0 = __shfl(i0, 63);
    if (lane < nb) bsum[lane] = i0 - a0;                    // exclusive
    if (64 + lane < nb) bsum[64 + lane] = tot0 + i1 - a1;
}

__global__ __launch_bounds__(256) void scan_emit(const int* __restrict__ cnt,
                                                 const int* __restrict__ boff,
                                                 int* __restrict__ row_dis,
                                                 int* __restrict__ row_drug,
                                                 float* __restrict__ inv_dis,
                                                 float* __restrict__ inv_drug) {
    __shared__ int wsum[4];
    int t = threadIdx.x, lane = t & 63, wid = t >> 6;
    int base = blockIdx.x * 1024 + t * 4;
    int4 c = make_int4(0, 0, 0, 0);
    if (base < NTOT) c = *reinterpret_cast<const int4*>(cnt + base);
    int sl = c.x + c.y + c.z + c.w;
    int sc = sl;
#pragma unroll
    for (int off = 1; off < 64; off <<= 1) {
        int tv = __shfl_up(sc, off);
        if (lane >= off) sc += tv;
    }
    if (lane == 63) wsum[wid] = sc;
    __syncthreads();
    int woff = 0;
    for (int w2 = 0; w2 < wid; ++w2) woff += wsum[w2];
    int run = boff[blockIdx.x] + woff + (sc - sl);   // exclusive prefix of this thread's 1st elem
    int cc[4] = { c.x, c.y, c.z, c.w };
    if (base < NTOT) {
#pragma unroll
        for (int k = 0; k < 4; ++k) {
            int i = base + k;
            float iv = 1.0f / (float)(cc[k] > 1 ? cc[k] : 1);
            if (i < NS) { row_dis[i] = run; inv_dis[i] = iv; }
            else        { row_drug[i - NS] = run - NE; inv_drug[i - NS] = iv; }
            run += cc[k];
        }
    }
    if (blockIdx.x == 0 && t == 0) { row_dis[NS] = NE; row_drug[ND] = NE; }
}

// place edges: plain stores, no atomic dependency; u16 payload
__global__ void place_kernel(const int* __restrict__ src, const int* __restrict__ dst,
                             const int* __restrict__ row_drug, const int* __restrict__ row_dis,
                             const unsigned short* __restrict__ rank_sd,
                             const unsigned short* __restrict__ rank_ds,
                             unsigned short* __restrict__ val_sd,
                             unsigned short* __restrict__ val_ds, int n) {
    int i = blockIdx.x * blockDim.x + threadIdx.x;
    if (i < n) {
        int s = src[i], d = dst[i];
        val_ds[row_dis[d] + (int)rank_ds[i]] = (unsigned short)s;
        val_sd[row_drug[s] + (int)rank_sd[i]] = (unsigned short)d;
    }
}

// ---------------- dtype prep ----------------

__global__ void convert_x(const float* __restrict__ xd, const float* __restrict__ xs,
                          unsigned short* __restrict__ outd, unsigned short* __restrict__ outs) {
    int i = (blockIdx.x * 256 + threadIdx.x) * 4;
    const int NDE = ND * 256;
    if (i < NDE) {
        float4 v = *reinterpret_cast<const float4*>(xd + i);
        ushort4 o; o.x = f2b(v.x); o.y = f2b(v.y); o.z = f2b(v.z); o.w = f2b(v.w);
        *reinterpret_cast<ushort4*>(outd + i) = o;
    } else {
        int j = i - NDE;
        float4 v = *reinterpret_cast<const float4*>(xs + j);
        ushort4 o; o.x = f2b(v.x); o.y = f2b(v.y); o.z = f2b(v.z); o.w = f2b(v.w);
        *reinterpret_cast<ushort4*>(outs + j) = o;
    }
}

struct W10 { const float* p[10]; };

// transpose ten 256x256 fp32 weight blocks into bf16 B^T tables [N][K]
__global__ void transpose_w(W10 s, unsigned short* __restrict__ dst) {
    int o = blockIdx.x * 256 + threadIdx.x;       // 655360 total
    int mat = o >> 16, idx = o & 65535;
    int n = idx >> 8, k = idx & 255;
    dst[o] = f2b(s.p[mat][k * 256 + n]);
}

// ---------------- XCD-pinned feature-chunked mean aggregation ----------------
// Work item = (node-group of 32, chunk c of 32 feats/64 B). Queue c is drained by
// blocks PHYSICALLY on XCD c (s_getreg HW_REG_XCC_ID), so XCD c's L2 only ever
// gathers byte-column [c*64, c*64+64) of the tables: hot set 3.2 MB (dis phase,
// drug rows) then 1.9 MB (drug phase, dis rows) -> L2-resident. Queue order is
// dis-groups first -> phases separate in time. Work-stealing ((xcc+1)&7, ...)
// guarantees full drain regardless of block->XCD distribution; each item is
// processed once, items write disjoint 64-B regions, per-item edge order is
// fixed -> deterministic output.
__global__ __launch_bounds__(256) void agg_xcd(const unsigned short* __restrict__ srcDis,
                                               const unsigned short* __restrict__ srcDrug,
                                               const int* __restrict__ row_dis,
                                               const int* __restrict__ row_drug,
                                               const unsigned short* __restrict__ val_ds,
                                               const unsigned short* __restrict__ val_sd,
                                               const float* __restrict__ inv_dis,
                                               const float* __restrict__ inv_drug,
                                               unsigned short* __restrict__ outDis,
                                               unsigned short* __restrict__ outDrug,
                                               int* __restrict__ qcnt) {
    unsigned xcc;
    asm volatile("s_getreg_b32 %0, hwreg(HW_REG_XCC_ID)" : "=s"(xcc));
    xcc &= 7;
    const int slot = threadIdx.x >> 3;      // node slot 0..31
    const int sub = threadIdx.x & 7;        // 8-B feature sub-chunk 0..7
    __shared__ int s_item;

    for (int qi = 0; qi < NCHUNK; ++qi) {
        const int q = (xcc + qi) & 7;       // chunk == queue
        for (;;) {
            if (threadIdx.x == 0) s_item = atomicAdd(&qcnt[q], 1);
            __syncthreads();
            const int g = s_item;
            __syncthreads();                // all read s_item before next overwrite
            if (g >= NGRP) break;
            int node = g * 32 + slot;       // NTOT = 2500*32 exact
            const unsigned short* xsrc; const int* row; const unsigned short* vals;
            const float* inv; unsigned short* outp;
            if (node < NS) {
                xsrc = srcDis; row = row_dis; vals = val_ds; inv = inv_dis; outp = outDis;
            } else {
                node -= NS;
                xsrc = srcDrug; row = row_drug; vals = val_sd; inv = inv_drug; outp = outDrug;
            }
            const int beg = row[node], end = row[node + 1];
            const int off = q * 32 + sub * 4;
            float a0 = 0.f, a1 = 0.f, a2 = 0.f, a3 = 0.f;
            int j = beg;
            for (; j + 4 <= end; j += 4) {
                int s0 = vals[j], s1 = vals[j + 1], s2 = vals[j + 2], s3 = vals[j + 3];
                ushort4 v0 = *reinterpret_cast<const ushort4*>(xsrc + s0 * 256 + off);
                ushort4 v1 = *reinterpret_cast<const ushort4*>(xsrc + s1 * 256 + off);
                ushort4 v2 = *reinterpret_cast<const ushort4*>(xsrc + s2 * 256 + off);
                ushort4 v3 = *reinterpret_cast<const ushort4*>(xsrc + s3 * 256 + off);
                a0 += b2f(v0.x) + b2f(v1.x) + b2f(v2.x) + b2f(v3.x);
                a1 += b2f(v0.y) + b2f(v1.y) + b2f(v2.y) + b2f(v3.y);
                a2 += b2f(v0.z) + b2f(v1.z) + b2f(v2.z) + b2f(v3.z);
                a3 += b2f(v0.w) + b2f(v1.w) + b2f(v2.w) + b2f(v3.w);
            }
            for (; j < end; ++j) {
                int s = vals[j];
                ushort4 v = *reinterpret_cast<const ushort4*>(xsrc + s * 256 + off);
                a0 += b2f(v.x); a1 += b2f(v.y); a2 += b2f(v.z); a3 += b2f(v.w);
            }
            const float iv = inv[node];
            ushort4 o;
            o.x = f2b(a0 * iv); o.y = f2b(a1 * iv); o.z = f2b(a2 * iv); o.w = f2b(a3 * iv);
            *reinterpret_cast<ushort4*>(outp + node * 256 + off) = o;
        }
    }
}

// ---------------- LDS-staged bf16 MFMA GEMM, two segments per dispatch ----------------

struct GemmSeg {
    const unsigned short* A1;
    const unsigned short* A2;
    const unsigned short* B1t;
    const unsigned short* B2t;
    const float* bias;
    unsigned short* C;
    int M; int relu; int nblk; int nsteps;   // nsteps: 8 = two passes, 4 = one pass
};

__global__ __launch_bounds__(256) void gemm_lds(GemmSeg sa, GemmSeg sb) {
    __shared__ unsigned short As[128 * 64];
    __shared__ unsigned short Bs[128 * 64];
    GemmSeg s;
    int bx = blockIdx.x;
    if (bx < sa.nblk) s = sa;
    else { s = sb; bx -= sa.nblk; }

    const int t = threadIdx.x;
    const int lane = t & 63, w = t >> 6;
    const int wr = w >> 1, wc = w & 1;
    const int fr = lane & 15, g = lane >> 4;
    const int bm0 = bx * 128;
    const int n0b = (int)blockIdx.y * 128;
    const int M = s.M;
    const int r8 = lane >> 3, slotL = lane & 7;   // staging: 8 lanes/row, 16B slots

    f32x4 acc[4][4];
#pragma unroll
    for (int m = 0; m < 4; ++m)
#pragma unroll
        for (int n = 0; n < 4; ++n)
            acc[m][n] = (f32x4){0.f, 0.f, 0.f, 0.f};

    for (int st = 0; st < s.nsteps; ++st) {
        const int k0 = (st & 3) * 64;
        const unsigned short* Ap = (st & 4) ? s.A2 : s.A1;
        const unsigned short* Bp = (st & 4) ? s.B2t : s.B1t;
#pragma unroll
        for (int j = 0; j < 4; ++j) {
            const int is = w * 4 + j;             // issue 0..15
            const int row = is * 8 + r8;          // LDS row 0..127
            const int sl = slotL ^ (row & 7);     // inverse-swizzled source slot
            int ra = bm0 + row; if (ra >= M) ra = M - 1;
            gload_lds16(Ap + (size_t)ra * 256 + k0 + sl * 8, &As[is * 512]);
            gload_lds16(Bp + (size_t)(n0b + row) * 256 + k0 + sl * 8, &Bs[is * 512]);
        }
        __syncthreads();   // compiler emits vmcnt(0) drain before barrier
#pragma unroll
        for (int kc = 0; kc < 2; ++kc) {
            const int q = kc * 4 + g;             // logical 16B k-slot
            short8 a[4], b[4];
#pragma unroll
            for (int n = 0; n < 4; ++n) {
                const int br = wc * 64 + n * 16 + fr;
                b[n] = *reinterpret_cast<const short8*>(&Bs[br * 64 + (q ^ (fr & 7)) * 8]);
            }
#pragma unroll
            for (int m = 0; m < 4; ++m) {
                const int ar = wr * 64 + m * 16 + fr;
                a[m] = *reinterpret_cast<const short8*>(&As[ar * 64 + (q ^ (fr & 7)) * 8]);
            }
#pragma unroll
            for (int m = 0; m < 4; ++m)
#pragma unroll
                for (int n = 0; n < 4; ++n)
                    acc[m][n] = __builtin_amdgcn_mfma_f32_16x16x32_bf16(a[m], b[n], acc[m][n], 0, 0, 0);
        }
        __syncthreads();   // WAR: all reads done before next stage overwrites
    }

    // epilogue: D row = base + g*4 + r, col = base + fr  [verified m89/m91]
#pragma unroll
    for (int n = 0; n < 4; ++n) {
        const int col = n0b + wc * 64 + n * 16 + fr;
        const float bv = s.bias ? s.bias[col] : 0.0f;
#pragma unroll
        for (int m = 0; m < 4; ++m) {
#pragma unroll
            for (int r = 0; r < 4; ++r) {
                int row = bm0 + wr * 64 + m * 16 + g * 4 + r;
                if (row < M) {
                    float v = acc[m][n][r] + bv;
                    if (s.relu) v = fmaxf(v, 0.f);
                    s.C[row * 256 + col] = f2b(v);
                }
            }
        }
    }
}

// ---------------- edge decoder: out[e] = relu(Pd[r]+Ps[c]+b1) . w2 + b2 ----------------

__global__ __launch_bounds__(256) void dec_edge(const unsigned short* __restrict__ Pd,
                                                const unsigned short* __restrict__ Ps,
                                                const int* __restrict__ lrow,
                                                const int* __restrict__ lcol,
                                                const float* __restrict__ b1,
                                                const float* __restrict__ w2,
                                                const float* __restrict__ b2,
                                                float* __restrict__ outp, int n) {
    int wid = threadIdx.x >> 6, lane = threadIdx.x & 63;
    int e = blockIdx.x * 4 + wid;
    if (e >= n) return;
    int r = lrow[e], c = lcol[e];
    const int off = lane * 4;
    ushort4 pd = *reinterpret_cast<const ushort4*>(Pd + r * 256 + off);
    ushort4 ps = *reinterpret_cast<const ushort4*>(Ps + c * 256 + off);
    float4 bb = *reinterpret_cast<const float4*>(b1 + off);
    float4 ww = *reinterpret_cast<const float4*>(w2 + off);
    float s = 0.f;
    s += fmaxf(b2f(pd.x) + b2f(ps.x) + bb.x, 0.f) * ww.x;
    s += fmaxf(b2f(pd.y) + b2f(ps.y) + bb.y, 0.f) * ww.y;
    s += fmaxf(b2f(pd.z) + b2f(ps.z) + bb.z, 0.f) * ww.z;
    s += fmaxf(b2f(pd.w) + b2f(ps.w) + bb.w, 0.f) * ww.w;
#pragma unroll
    for (int o = 32; o; o >>= 1) s += __shfl_down(s, o);
    if (lane == 0) outp[e] = s + b2[0];
}

// ---------------- launch ----------------

extern "C" void kernel_launch(void* const* d_in, const int* in_sizes, int n_in,
                              void* d_out, int out_size, void* d_ws, size_t ws_size,
                              hipStream_t stream) {
    const float* x_drug = (const float*)d_in[0];
    const float* x_dis  = (const float*)d_in[1];
    const int* esrc = (const int*)d_in[2];
    const int* edst = (const int*)d_in[3];
    const int* lrow = (const int*)d_in[4];
    const int* lcol = (const int*)d_in[5];
    const float* Wl1_ds = (const float*)d_in[6];
    const float* bl1_ds = (const float*)d_in[7];
    const float* Wr1_ds = (const float*)d_in[8];
    const float* Wl1_sd = (const float*)d_in[9];
    const float* bl1_sd = (const float*)d_in[10];
    const float* Wr1_sd = (const float*)d_in[11];
    const float* Wl2_ds = (const float*)d_in[12];
    const float* bl2_ds = (const float*)d_in[13];
    const float* Wr2_ds = (const float*)d_in[14];
    const float* Wl2_sd = (const float*)d_in[15];
    const float* bl2_sd = (const float*)d_in[16];
    const float* Wr2_sd = (const float*)d_in[17];
    const float* Wdec1 = (const float*)d_in[18];
    const float* bdec1 = (const float*)d_in[19];
    const float* Wdec2 = (const float*)d_in[20];
    const float* bdec2 = (const float*)d_in[21];
    float* outp = (float*)d_out;

    char* ws = (char*)d_ws;
    size_t off = 0;
    auto alloc = [&](size_t bytes) -> void* {
        void* p = ws + off;
        off = (off + bytes + 255) & ~(size_t)255;
        return p;
    };
    int* cnt       = (int*)alloc((size_t)(NTOT + 16) * 4); // [cnt_dis | cnt_drug | qcnt1 | qcnt2]
    int* bsum      = (int*)alloc((size_t)SCAN_BLK * 4);
    int* row_dis   = (int*)alloc((size_t)(NS + 1) * 4);
    int* row_drug  = (int*)alloc((size_t)(ND + 1) * 4);
    float* inv_dis = (float*)alloc((size_t)NS * 4);
    float* inv_drug= (float*)alloc((size_t)ND * 4);
    unsigned short* rank_ds = (unsigned short*)alloc((size_t)NE * 2);
    unsigned short* rank_sd = (unsigned short*)alloc((size_t)NE * 2);
    unsigned short* val_ds  = (unsigned short*)alloc((size_t)NE * 2);
    unsigned short* val_sd  = (unsigned short*)alloc((size_t)NE * 2);
    unsigned short* Wt   = (unsigned short*)alloc((size_t)10 * 65536 * 2);
    unsigned short* xd_b = (unsigned short*)alloc((size_t)ND * 256 * 2);
    unsigned short* xs_b = (unsigned short*)alloc((size_t)NS * 256 * 2);
    unsigned short* aggs = (unsigned short*)alloc((size_t)NS * 256 * 2);  // dis-dst agg
    unsigned short* aggd = (unsigned short*)alloc((size_t)ND * 256 * 2);  // drug-dst agg
    unsigned short* zd1  = (unsigned short*)alloc((size_t)ND * 256 * 2);
    unsigned short* zs1  = (unsigned short*)alloc((size_t)NS * 256 * 2);
    unsigned short* zd2  = (unsigned short*)alloc((size_t)ND * 256 * 2);
    unsigned short* zs2  = (unsigned short*)alloc((size_t)NS * 256 * 2);
    unsigned short* Pd   = (unsigned short*)alloc((size_t)ND * 256 * 2);
    unsigned short* Ps   = (unsigned short*)alloc((size_t)NS * 256 * 2);
    int* cnt_dis = cnt;
    int* cnt_drug = cnt + NS;
    int* qcnt1 = cnt + NTOT;
    int* qcnt2 = cnt + NTOT + 8;

    // --- dtype prep (independent of CSR) ---
    convert_x<<<(ND + NS) * 256 / 1024, 256, 0, stream>>>(x_drug, x_dis, xd_b, xs_b);
    W10 wsrc;
    wsrc.p[0] = Wl1_ds; wsrc.p[1] = Wr1_ds; wsrc.p[2] = Wl1_sd; wsrc.p[3] = Wr1_sd;
    wsrc.p[4] = Wl2_ds; wsrc.p[5] = Wr2_ds; wsrc.p[6] = Wl2_sd; wsrc.p[7] = Wr2_sd;
    wsrc.p[8] = Wdec1;                 // rows 0..255  (zd part)
    wsrc.p[9] = Wdec1 + 256 * 256;     // rows 256..511 (zs part)
    transpose_w<<<2560, 256, 0, stream>>>(wsrc, Wt);
    unsigned short* WT[10];
    for (int i = 0; i < 10; ++i) WT[i] = Wt + (size_t)i * 65536;

    // --- CSR build ---
    zero_kernel<<<(NTOT + 16 + 255) / 256, 256, 0, stream>>>(cnt, NTOT + 16);
    rank_kernel<<<(NE + 255) / 256, 256, 0, stream>>>(esrc, edst, cnt_drug, cnt_dis,
                                                      rank_sd, rank_ds, NE);
    scan_part<<<SCAN_BLK, 256, 0, stream>>>(cnt, bsum);
    scan_top<<<1, 64, 0, stream>>>(bsum, SCAN_BLK);
    scan_emit<<<SCAN_BLK, 256, 0, stream>>>(cnt, bsum, row_dis, row_drug, inv_dis, inv_drug);
    place_kernel<<<(NE + 255) / 256, 256, 0, stream>>>(esrc, edst, row_drug, row_dis,
                                                       rank_sd, rank_ds, val_sd, val_ds, NE);

    const int AGG_GRID = 2048;     // 8 persistent blocks/CU
    const int NB_NS = (NS + 127) / 128, NB_ND = (ND + 127) / 128;
    dim3 gemm_grid(NB_NS + NB_ND, 2);

    // --- layer 1 (relu) ---
    agg_xcd<<<AGG_GRID, 256, 0, stream>>>(xd_b, xs_b, row_dis, row_drug, val_ds, val_sd,
                                          inv_dis, inv_drug, aggs, aggd, qcnt1);
    {
        GemmSeg a = { aggs, xs_b, WT[0], WT[1], bl1_ds, zs1, NS, 1, NB_NS, 8 };
        GemmSeg b = { aggd, xd_b, WT[2], WT[3], bl1_sd, zd1, ND, 1, NB_ND, 8 };
        gemm_lds<<<gemm_grid, 256, 0, stream>>>(a, b);
    }

    // --- layer 2 (no relu) ---
    agg_xcd<<<AGG_GRID, 256, 0, stream>>>(zd1, zs1, row_dis, row_drug, val_ds, val_sd,
                                          inv_dis, inv_drug, aggs, aggd, qcnt2);
    {
        GemmSeg a = { aggs, zs1, WT[4], WT[5], bl2_ds, zs2, NS, 0, NB_NS, 8 };
        GemmSeg b = { aggd, zd1, WT[6], WT[7], bl2_sd, zd2, ND, 0, NB_ND, 8 };
        gemm_lds<<<gemm_grid, 256, 0, stream>>>(a, b);
    }

    // --- decoder projections (fused, single pass) ---
    {
        GemmSeg a = { zd2, nullptr, WT[8], nullptr, nullptr, Pd, ND, 0, NB_ND, 4 };
        GemmSeg b = { zs2, nullptr, WT[9], nullptr, nullptr, Ps, NS, 0, NB_NS, 4 };
        gemm_lds<<<gemm_grid, 256, 0, stream>>>(a, b);
    }
    dec_edge<<<(EL + 3) / 4, 256, 0, stream>>>(Pd, Ps, lrow, lcol, bdec1, Wdec2, bdec2, outp, EL);
}

// Round 9
// 600.460 us; speedup vs baseline: 2.0453x; 2.0453x over previous
//
#include <hip/hip_runtime.h>
#include <hip/hip_bf16.h>

#define ND 50000
#define NS 30000
#define NE 1000000
#define EL 200000
#define NTOT (NS + ND)          // 80000
#define SCAN_BLK ((NTOT + 1023) / 1024)   // 79

typedef short short8 __attribute__((ext_vector_type(8)));
typedef float f32x4 __attribute__((ext_vector_type(4)));

__device__ __forceinline__ float b2f(unsigned short u) {
    union { unsigned int i; float f; } c; c.i = ((unsigned int)u) << 16; return c.f;
}
__device__ __forceinline__ unsigned short f2b(float f) {
    __hip_bfloat16 h = __float2bfloat16(f);   // RNE
    union { __hip_bfloat16 h; unsigned short u; } c; c.h = h; return c.u;
}

// async global->LDS, 16 B per lane; LDS dest is wave-uniform base + lane*16
__device__ __forceinline__ void gload_lds16(const unsigned short* g, unsigned short* l) {
    __builtin_amdgcn_global_load_lds(
        (const __attribute__((address_space(1))) unsigned int*)g,
        (__attribute__((address_space(3))) unsigned int*)l, 16, 0, 0);
}

// ---------------- CSR build ----------------

__global__ void zero_kernel(int* a, int n) {
    int i = blockIdx.x * blockDim.x + threadIdx.x;
    if (i < n) a[i] = 0;
}

// histogram + per-edge rank in one pass (atomic return IS the rank)
__global__ void rank_kernel(const int* __restrict__ src, const int* __restrict__ dst,
                            int* cnt_drug, int* cnt_dis,
                            unsigned short* __restrict__ rank_sd,
                            unsigned short* __restrict__ rank_ds, int n) {
    int i = blockIdx.x * blockDim.x + threadIdx.x;
    if (i < n) {
        int s = src[i], d = dst[i];
        rank_ds[i] = (unsigned short)atomicAdd(&cnt_dis[d], 1);
        rank_sd[i] = (unsigned short)atomicAdd(&cnt_drug[s], 1);
    }
}

// hierarchical scan over concatenated [cnt_dis | cnt_drug] (NTOT ints)
__global__ __launch_bounds__(256) void scan_part(const int* __restrict__ cnt,
                                                 int* __restrict__ bsum) {
    __shared__ int red[4];
    int t = threadIdx.x, lane = t & 63, wid = t >> 6;
    int base = blockIdx.x * 1024 + t * 4;
    int s = 0;
    if (base < NTOT) {           // NTOT % 4 == 0 -> whole int4 in bounds
        int4 c = *reinterpret_cast<const int4*>(cnt + base);
        s = c.x + c.y + c.z + c.w;
    }
#pragma unroll
    for (int off = 32; off; off >>= 1) s += __shfl_down(s, off);
    if (lane == 0) red[wid] = s;
    __syncthreads();
    if (t == 0) bsum[blockIdx.x] = red[0] + red[1] + red[2] + red[3];
}

__global__ void scan_top(int* bsum, int nb) {   // 1 block x 64 threads, nb <= 128
    int lane = threadIdx.x;
    int a0 = lane < nb ? bsum[lane] : 0;
    int a1 = (64 + lane) < nb ? bsum[64 + lane] : 0;
    int i0 = a0, i1 = a1;
#pragma unroll
    for (int off = 1; off < 64; off <<= 1) {
        int t0 = __shfl_up(i0, off);
        int t1 = __shfl_up(i1, off);
        if (lane >= off) { i0 += t0; i1 += t1; }
    }
    int tot0 = __shfl(i0, 63);
    if (lane < nb) bsum[lane] = i0 - a0;                    // exclusive
    if (64 + lane < nb) bsum[64 + lane] = tot0 + i1 - a1;
}

__global__ __launch_bounds__(256) void scan_emit(const int* __restrict__ cnt,
                                                 const int* __restrict__ boff,
                                                 int* __restrict__ row_dis,
                                                 int* __restrict__ row_drug,
                                                 float* __restrict__ inv_dis,
                                                 float* __restrict__ inv_drug) {
    __shared__ int wsum[4];
    int t = threadIdx.x, lane = t & 63, wid = t >> 6;
    int base = blockIdx.x * 1024 + t * 4;
    int4 c = make_int4(0, 0, 0, 0);
    if (base < NTOT) c = *reinterpret_cast<const int4*>(cnt + base);
    int sl = c.x + c.y + c.z + c.w;
    int sc = sl;
#pragma unroll
    for (int off = 1; off < 64; off <<= 1) {
        int tv = __shfl_up(sc, off);
        if (lane >= off) sc += tv;
    }
    if (lane == 63) wsum[wid] = sc;
    __syncthreads();
    int woff = 0;
    for (int w2 = 0; w2 < wid; ++w2) woff += wsum[w2];
    int run = boff[blockIdx.x] + woff + (sc - sl);   // exclusive prefix of this thread's 1st elem
    int cc[4] = { c.x, c.y, c.z, c.w };
    if (base < NTOT) {
#pragma unroll
        for (int k = 0; k < 4; ++k) {
            int i = base + k;
            float iv = 1.0f / (float)(cc[k] > 1 ? cc[k] : 1);
            if (i < NS) { row_dis[i] = run; inv_dis[i] = iv; }
            else        { row_drug[i - NS] = run - NE; inv_drug[i - NS] = iv; }
            run += cc[k];
        }
    }
    if (blockIdx.x == 0 && t == 0) { row_dis[NS] = NE; row_drug[ND] = NE; }
}

// place edges: plain stores, no atomic dependency; u16 payload
__global__ void place_kernel(const int* __restrict__ src, const int* __restrict__ dst,
                             const int* __restrict__ row_drug, const int* __restrict__ row_dis,
                             const unsigned short* __restrict__ rank_sd,
                             const unsigned short* __restrict__ rank_ds,
                             unsigned short* __restrict__ val_sd,
                             unsigned short* __restrict__ val_ds, int n) {
    int i = blockIdx.x * blockDim.x + threadIdx.x;
    if (i < n) {
        int s = src[i], d = dst[i];
        val_ds[row_dis[d] + (int)rank_ds[i]] = (unsigned short)s;
        val_sd[row_drug[s] + (int)rank_sd[i]] = (unsigned short)d;
    }
}

// ---------------- dtype prep ----------------

__global__ void convert_x(const float* __restrict__ xd, const float* __restrict__ xs,
                          unsigned short* __restrict__ outd, unsigned short* __restrict__ outs) {
    int i = (blockIdx.x * 256 + threadIdx.x) * 4;
    const int NDE = ND * 256;
    if (i < NDE) {
        float4 v = *reinterpret_cast<const float4*>(xd + i);
        ushort4 o; o.x = f2b(v.x); o.y = f2b(v.y); o.z = f2b(v.z); o.w = f2b(v.w);
        *reinterpret_cast<ushort4*>(outd + i) = o;
    } else {
        int j = i - NDE;
        float4 v = *reinterpret_cast<const float4*>(xs + j);
        ushort4 o; o.x = f2b(v.x); o.y = f2b(v.y); o.z = f2b(v.z); o.w = f2b(v.w);
        *reinterpret_cast<ushort4*>(outs + j) = o;
    }
}

struct W10 { const float* p[10]; };

// transpose ten 256x256 fp32 weight blocks into bf16 B^T tables [N][K]
__global__ void transpose_w(W10 s, unsigned short* __restrict__ dst) {
    int o = blockIdx.x * 256 + threadIdx.x;       // 655360 total
    int mat = o >> 16, idx = o & 65535;
    int n = idx >> 8, k = idx & 255;
    dst[o] = f2b(s.p[mat][k * 256 + n]);
}

// ---------------- fused mean aggregation, 2 rows/wave-load, 8 rows in flight ----------------

__global__ __launch_bounds__(256) void agg_bf2(const unsigned short* __restrict__ srcDis,
                                               const unsigned short* __restrict__ srcDrug,
                                               const int* __restrict__ row_dis,
                                               const int* __restrict__ row_drug,
                                               const unsigned short* __restrict__ val_ds,
                                               const unsigned short* __restrict__ val_sd,
                                               const float* __restrict__ inv_dis,
                                               const float* __restrict__ inv_drug,
                                               unsigned short* __restrict__ outDis,
                                               unsigned short* __restrict__ outDrug) {
    int wid = threadIdx.x >> 6, lane = threadIdx.x & 63;
    int node = blockIdx.x * 4 + wid;
    const int half = lane >> 5;          // 0: row j, 1: row j+1
    const int sub = lane & 31;           // feature chunk [sub*8, sub*8+8)
    const unsigned short* xsrc; const int* row; const unsigned short* vals;
    const float* inv; unsigned short* outp;
    if (node < NS) {
        xsrc = srcDis; row = row_dis; vals = val_ds; inv = inv_dis; outp = outDis;
    } else {
        node -= NS;
        if (node >= ND) return;
        xsrc = srcDrug; row = row_drug; vals = val_sd; inv = inv_drug; outp = outDrug;
    }
    const int beg = row[node], end = row[node + 1];
    const int off = sub * 8;
    float a[8] = {};
    int j = beg;
    for (; j + 8 <= end; j += 8) {
        int r0 = vals[j     + half];
        int r1 = vals[j + 2 + half];
        int r2 = vals[j + 4 + half];
        int r3 = vals[j + 6 + half];
        short8 v0 = *reinterpret_cast<const short8*>(xsrc + r0 * 256 + off);
        short8 v1 = *reinterpret_cast<const short8*>(xsrc + r1 * 256 + off);
        short8 v2 = *reinterpret_cast<const short8*>(xsrc + r2 * 256 + off);
        short8 v3 = *reinterpret_cast<const short8*>(xsrc + r3 * 256 + off);
#pragma unroll
        for (int k = 0; k < 8; ++k)
            a[k] += b2f((unsigned short)v0[k]) + b2f((unsigned short)v1[k])
                  + b2f((unsigned short)v2[k]) + b2f((unsigned short)v3[k]);
    }
    for (; j + 2 <= end; j += 2) {
        int r = vals[j + half];
        short8 v = *reinterpret_cast<const short8*>(xsrc + r * 256 + off);
#pragma unroll
        for (int k = 0; k < 8; ++k) a[k] += b2f((unsigned short)v[k]);
    }
    if (j < end && half == 0) {          // odd tail: lanes 0-31 only
        int r = vals[j];
        short8 v = *reinterpret_cast<const short8*>(xsrc + r * 256 + off);
#pragma unroll
        for (int k = 0; k < 8; ++k) a[k] += b2f((unsigned short)v[k]);
    }
#pragma unroll
    for (int k = 0; k < 8; ++k) a[k] += __shfl_xor(a[k], 32);
    if (half == 0) {
        const float iv = inv[node];
        short8 o;
#pragma unroll
        for (int k = 0; k < 8; ++k) o[k] = (short)f2b(a[k] * iv);
        *reinterpret_cast<short8*>(outp + node * 256 + off) = o;
    }
}

// ---------------- LDS-staged bf16 MFMA GEMM, 2-phase double-buffered ----------------
// Per segment: C[M,256] = act( A1@B1 (+ A2@B2) + bias ). Tile 128(M)x128(N), BK=64,
// 4 waves 2x2. T3-minimum schedule: prologue stage buf0; loop { STAGE(buf^1, st+1);
// ds_read+MFMA from buf; barrier (drains prefetch vmcnt + read lgkm) }. One barrier
// per K-step; stage latency hides under 32 MFMAs. XOR swizzle slot^=(row&7) on the
// GLOBAL SOURCE (LDS dest linear, rule #21), same XOR on ds_read. K order unchanged
// -> bit-identical output.

struct GemmSeg {
    const unsigned short* A1;
    const unsigned short* A2;
    const unsigned short* B1t;
    const unsigned short* B2t;
    const float* bias;
    unsigned short* C;
    int M; int relu; int nblk; int nsteps;   // nsteps: 8 = two passes, 4 = one pass
};

__global__ __launch_bounds__(256) void gemm_lds(GemmSeg sa, GemmSeg sb) {
    __shared__ unsigned short As[2][128 * 64];
    __shared__ unsigned short Bs[2][128 * 64];
    GemmSeg s;
    int bx = blockIdx.x;
    if (bx < sa.nblk) s = sa;
    else { s = sb; bx -= sa.nblk; }

    const int t = threadIdx.x;
    const int lane = t & 63, w = t >> 6;
    const int wr = w >> 1, wc = w & 1;
    const int fr = lane & 15, g = lane >> 4;
    const int bm0 = bx * 128;
    const int n0b = (int)blockIdx.y * 128;
    const int M = s.M;
    const int r8 = lane >> 3, slotL = lane & 7;   // staging: 8 lanes/row, 16B slots

    // precompute per-issue source offsets (rows fixed across steps)
    int raOff[4]; int rbOff[4];
#pragma unroll
    for (int j = 0; j < 4; ++j) {
        const int is = w * 4 + j;
        const int row = is * 8 + r8;
        const int sl = slotL ^ (row & 7);
        int ra = bm0 + row; if (ra >= M) ra = M - 1;
        raOff[j] = ra * 256 + sl * 8;
        rbOff[j] = (n0b + row) * 256 + sl * 8;
    }

    f32x4 acc[4][4];
#pragma unroll
    for (int m = 0; m < 4; ++m)
#pragma unroll
        for (int n = 0; n < 4; ++n)
            acc[m][n] = (f32x4){0.f, 0.f, 0.f, 0.f};

    const int nsteps = s.nsteps;
    // prologue: stage step 0 into buf 0
    {
        const unsigned short* Ap = s.A1;
        const unsigned short* Bp = s.B1t;
#pragma unroll
        for (int j = 0; j < 4; ++j) {
            const int is = w * 4 + j;
            gload_lds16(Ap + raOff[j], &As[0][is * 512]);
            gload_lds16(Bp + rbOff[j], &Bs[0][is * 512]);
        }
    }
    __syncthreads();

    for (int st = 0; st < nsteps; ++st) {
        const int cur = st & 1;
        // prefetch next step into the other buffer (before compute)
        if (st + 1 < nsteps) {
            const int k1 = ((st + 1) & 3) * 64;
            const unsigned short* Ap = ((st + 1) & 4) ? s.A2 : s.A1;
            const unsigned short* Bp = ((st + 1) & 4) ? s.B2t : s.B1t;
#pragma unroll
            for (int j = 0; j < 4; ++j) {
                const int is = w * 4 + j;
                gload_lds16(Ap + raOff[j] + k1, &As[cur ^ 1][is * 512]);
                gload_lds16(Bp + rbOff[j] + k1, &Bs[cur ^ 1][is * 512]);
            }
        }
        // compute current buffer: 2 x 16 MFMA
#pragma unroll
        for (int kc = 0; kc < 2; ++kc) {
            const int q = kc * 4 + g;             // logical 16B k-slot
            short8 a[4], b[4];
#pragma unroll
            for (int n = 0; n < 4; ++n) {
                const int br = wc * 64 + n * 16 + fr;
                b[n] = *reinterpret_cast<const short8*>(&Bs[cur][br * 64 + (q ^ (fr & 7)) * 8]);
            }
#pragma unroll
            for (int m = 0; m < 4; ++m) {
                const int ar = wr * 64 + m * 16 + fr;
                a[m] = *reinterpret_cast<const short8*>(&As[cur][ar * 64 + (q ^ (fr & 7)) * 8]);
            }
#pragma unroll
            for (int m = 0; m < 4; ++m)
#pragma unroll
                for (int n = 0; n < 4; ++n)
                    acc[m][n] = __builtin_amdgcn_mfma_f32_16x16x32_bf16(a[m], b[n], acc[m][n], 0, 0, 0);
        }
        __syncthreads();   // drains prefetch (vmcnt) + ds reads; buf swap safe
    }

    // epilogue: D row = base + g*4 + r, col = base + fr  [verified m89/m91]
#pragma unroll
    for (int n = 0; n < 4; ++n) {
        const int col = n0b + wc * 64 + n * 16 + fr;
        const float bv = s.bias ? s.bias[col] : 0.0f;
#pragma unroll
        for (int m = 0; m < 4; ++m) {
#pragma unroll
            for (int r = 0; r < 4; ++r) {
                int row = bm0 + wr * 64 + m * 16 + g * 4 + r;
                if (row < M) {
                    float v = acc[m][n][r] + bv;
                    if (s.relu) v = fmaxf(v, 0.f);
                    s.C[row * 256 + col] = f2b(v);
                }
            }
        }
    }
}

// ---------------- edge decoder: out[e] = relu(Pd[r]+Ps[c]+b1) . w2 + b2 ----------------

__global__ __launch_bounds__(256) void dec_edge(const unsigned short* __restrict__ Pd,
                                                const unsigned short* __restrict__ Ps,
                                                const int* __restrict__ lrow,
                                                const int* __restrict__ lcol,
                                                const float* __restrict__ b1,
                                                const float* __restrict__ w2,
                                                const float* __restrict__ b2,
                                                float* __restrict__ outp, int n) {
    int wid = threadIdx.x >> 6, lane = threadIdx.x & 63;
    int e = blockIdx.x * 4 + wid;
    if (e >= n) return;
    int r = lrow[e], c = lcol[e];
    const int off = lane * 4;
    ushort4 pd = *reinterpret_cast<const ushort4*>(Pd + r * 256 + off);
    ushort4 ps = *reinterpret_cast<const ushort4*>(Ps + c * 256 + off);
    float4 bb = *reinterpret_cast<const float4*>(b1 + off);
    float4 ww = *reinterpret_cast<const float4*>(w2 + off);
    float s = 0.f;
    s += fmaxf(b2f(pd.x) + b2f(ps.x) + bb.x, 0.f) * ww.x;
    s += fmaxf(b2f(pd.y) + b2f(ps.y) + bb.y, 0.f) * ww.y;
    s += fmaxf(b2f(pd.z) + b2f(ps.z) + bb.z, 0.f) * ww.z;
    s += fmaxf(b2f(pd.w) + b2f(ps.w) + bb.w, 0.f) * ww.w;
#pragma unroll
    for (int o = 32; o; o >>= 1) s += __shfl_down(s, o);
    if (lane == 0) outp[e] = s + b2[0];
}

// ---------------- launch ----------------

extern "C" void kernel_launch(void* const* d_in, const int* in_sizes, int n_in,
                              void* d_out, int out_size, void* d_ws, size_t ws_size,
                              hipStream_t stream) {
    const float* x_drug = (const float*)d_in[0];
    const float* x_dis  = (const float*)d_in[1];
    const int* esrc = (const int*)d_in[2];
    const int* edst = (const int*)d_in[3];
    const int* lrow = (const int*)d_in[4];
    const int* lcol = (const int*)d_in[5];
    const float* Wl1_ds = (const float*)d_in[6];
    const float* bl1_ds = (const float*)d_in[7];
    const float* Wr1_ds = (const float*)d_in[8];
    const float* Wl1_sd = (const float*)d_in[9];
    const float* bl1_sd = (const float*)d_in[10];
    const float* Wr1_sd = (const float*)d_in[11];
    const float* Wl2_ds = (const float*)d_in[12];
    const float* bl2_ds = (const float*)d_in[13];
    const float* Wr2_ds = (const float*)d_in[14];
    const float* Wl2_sd = (const float*)d_in[15];
    const float* bl2_sd = (const float*)d_in[16];
    const float* Wr2_sd = (const float*)d_in[17];
    const float* Wdec1 = (const float*)d_in[18];
    const float* bdec1 = (const float*)d_in[19];
    const float* Wdec2 = (const float*)d_in[20];
    const float* bdec2 = (const float*)d_in[21];
    float* outp = (float*)d_out;

    char* ws = (char*)d_ws;
    size_t off = 0;
    auto alloc = [&](size_t bytes) -> void* {
        void* p = ws + off;
        off = (off + bytes + 255) & ~(size_t)255;
        return p;
    };
    int* cnt       = (int*)alloc((size_t)NTOT * 4);      // [cnt_dis | cnt_drug]
    int* bsum      = (int*)alloc((size_t)SCAN_BLK * 4);
    int* row_dis   = (int*)alloc((size_t)(NS + 1) * 4);
    int* row_drug  = (int*)alloc((size_t)(ND + 1) * 4);
    float* inv_dis = (float*)alloc((size_t)NS * 4);
    float* inv_drug= (float*)alloc((size_t)ND * 4);
    unsigned short* rank_ds = (unsigned short*)alloc((size_t)NE * 2);
    unsigned short* rank_sd = (unsigned short*)alloc((size_t)NE * 2);
    unsigned short* val_ds  = (unsigned short*)alloc((size_t)NE * 2);
    unsigned short* val_sd  = (unsigned short*)alloc((size_t)NE * 2);
    unsigned short* Wt   = (unsigned short*)alloc((size_t)10 * 65536 * 2);
    unsigned short* xd_b = (unsigned short*)alloc((size_t)ND * 256 * 2);
    unsigned short* xs_b = (unsigned short*)alloc((size_t)NS * 256 * 2);
    unsigned short* aggs = (unsigned short*)alloc((size_t)NS * 256 * 2);  // dis-dst agg
    unsigned short* aggd = (unsigned short*)alloc((size_t)ND * 256 * 2);  // drug-dst agg
    unsigned short* zd1  = (unsigned short*)alloc((size_t)ND * 256 * 2);
    unsigned short* zs1  = (unsigned short*)alloc((size_t)NS * 256 * 2);
    unsigned short* zd2  = (unsigned short*)alloc((size_t)ND * 256 * 2);
    unsigned short* zs2  = (unsigned short*)alloc((size_t)NS * 256 * 2);
    unsigned short* Pd   = (unsigned short*)alloc((size_t)ND * 256 * 2);
    unsigned short* Ps   = (unsigned short*)alloc((size_t)NS * 256 * 2);
    int* cnt_dis = cnt;
    int* cnt_drug = cnt + NS;

    // --- dtype prep (independent of CSR) ---
    convert_x<<<(ND + NS) * 256 / 1024, 256, 0, stream>>>(x_drug, x_dis, xd_b, xs_b);
    W10 wsrc;
    wsrc.p[0] = Wl1_ds; wsrc.p[1] = Wr1_ds; wsrc.p[2] = Wl1_sd; wsrc.p[3] = Wr1_sd;
    wsrc.p[4] = Wl2_ds; wsrc.p[5] = Wr2_ds; wsrc.p[6] = Wl2_sd; wsrc.p[7] = Wr2_sd;
    wsrc.p[8] = Wdec1;                 // rows 0..255  (zd part)
    wsrc.p[9] = Wdec1 + 256 * 256;     // rows 256..511 (zs part)
    transpose_w<<<2560, 256, 0, stream>>>(wsrc, Wt);
    unsigned short* WT[10];
    for (int i = 0; i < 10; ++i) WT[i] = Wt + (size_t)i * 65536;

    // --- CSR build ---
    zero_kernel<<<(NTOT + 255) / 256, 256, 0, stream>>>(cnt, NTOT);
    rank_kernel<<<(NE + 255) / 256, 256, 0, stream>>>(esrc, edst, cnt_drug, cnt_dis,
                                                      rank_sd, rank_ds, NE);
    scan_part<<<SCAN_BLK, 256, 0, stream>>>(cnt, bsum);
    scan_top<<<1, 64, 0, stream>>>(bsum, SCAN_BLK);
    scan_emit<<<SCAN_BLK, 256, 0, stream>>>(cnt, bsum, row_dis, row_drug, inv_dis, inv_drug);
    place_kernel<<<(NE + 255) / 256, 256, 0, stream>>>(esrc, edst, row_drug, row_dis,
                                                       rank_sd, rank_ds, val_sd, val_ds, NE);

    const int AGG_GRID = (NTOT + 3) / 4;
    const int NB_NS = (NS + 127) / 128, NB_ND = (ND + 127) / 128;
    dim3 gemm_grid(NB_NS + NB_ND, 2);

    // --- layer 1 (relu) ---
    agg_bf2<<<AGG_GRID, 256, 0, stream>>>(xd_b, xs_b, row_dis, row_drug, val_ds, val_sd,
                                          inv_dis, inv_drug, aggs, aggd);
    {
        GemmSeg a = { aggs, xs_b, WT[0], WT[1], bl1_ds, zs1, NS, 1, NB_NS, 8 };
        GemmSeg b = { aggd, xd_b, WT[2], WT[3], bl1_sd, zd1, ND, 1, NB_ND, 8 };
        gemm_lds<<<gemm_grid, 256, 0, stream>>>(a, b);
    }

    // --- layer 2 (no relu) ---
    agg_bf2<<<AGG_GRID, 256, 0, stream>>>(zd1, zs1, row_dis, row_drug, val_ds, val_sd,
                                          inv_dis, inv_drug, aggs, aggd);
    {
        GemmSeg a = { aggs, zs1, WT[4], WT[5], bl2_ds, zs2, NS, 0, NB_NS, 8 };
        GemmSeg b = { aggd, zd1, WT[6], WT[7], bl2_sd, zd2, ND, 0, NB_ND, 8 };
        gemm_lds<<<gemm_grid, 256, 0, stream>>>(a, b);
    }

    // --- decoder projections (fused, single pass) ---
    {
        GemmSeg a = { zd2, nullptr, WT[8], nullptr, nullptr, Pd, ND, 0, NB_ND, 4 };
        GemmSeg b = { zs2, nullptr, WT[9], nullptr, nullptr, Ps, NS, 0, NB_NS, 4 };
        gemm_lds<<<gemm_grid, 256, 0, stream>>>(a, b);
    }
    dec_edge<<<(EL + 3) / 4, 256, 0, stream>>>(Pd, Ps, lrow, lcol, bdec1, Wdec2, bdec2, outp, EL);
}

// Round 10
// 569.692 us; speedup vs baseline: 2.1558x; 1.0540x over previous
//
#include <hip/hip_runtime.h>
#include <hip/hip_bf16.h>

#define ND 50000
#define NS 30000
#define NE 1000000
#define EL 200000
#define NTOT (NS + ND)          // 80000
#define SCAN_BLK ((NTOT + 1023) / 1024)   // 79
#define CONV_BLKS 20000         // (ND+NS)*256 elems / 1024 per block
#define TRW_BLKS 2560
#define ZERO_BLKS ((NTOT + 255) / 256)

typedef short short8 __attribute__((ext_vector_type(8)));
typedef float f32x4 __attribute__((ext_vector_type(4)));

__device__ __forceinline__ float b2f(unsigned short u) {
    union { unsigned int i; float f; } c; c.i = ((unsigned int)u) << 16; return c.f;
}
__device__ __forceinline__ unsigned short f2b(float f) {
    __hip_bfloat16 h = __float2bfloat16(f);   // RNE
    union { __hip_bfloat16 h; unsigned short u; } c; c.h = h; return c.u;
}

// async global->LDS, 16 B per lane; LDS dest is wave-uniform base + lane*16
__device__ __forceinline__ void gload_lds16(const unsigned short* g, unsigned short* l) {
    __builtin_amdgcn_global_load_lds(
        (const __attribute__((address_space(1))) unsigned int*)g,
        (__attribute__((address_space(3))) unsigned int*)l, 16, 0, 0);
}

struct W10 { const float* p[10]; };

// ---------------- fused prep: convert x to bf16 + transpose weights + zero counters ----------------

__global__ void prep_kernel(const float* __restrict__ xd, const float* __restrict__ xs,
                            unsigned short* __restrict__ outd, unsigned short* __restrict__ outs,
                            W10 wsrc, unsigned short* __restrict__ wdst,
                            int* __restrict__ cnt) {
    int b = blockIdx.x, t = threadIdx.x;
    if (b < CONV_BLKS) {
        int i = (b * 256 + t) * 4;
        const int NDE = ND * 256;
        if (i < NDE) {
            float4 v = *reinterpret_cast<const float4*>(xd + i);
            ushort4 o; o.x = f2b(v.x); o.y = f2b(v.y); o.z = f2b(v.z); o.w = f2b(v.w);
            *reinterpret_cast<ushort4*>(outd + i) = o;
        } else {
            int j = i - NDE;
            float4 v = *reinterpret_cast<const float4*>(xs + j);
            ushort4 o; o.x = f2b(v.x); o.y = f2b(v.y); o.z = f2b(v.z); o.w = f2b(v.w);
            *reinterpret_cast<ushort4*>(outs + j) = o;
        }
    } else if (b < CONV_BLKS + TRW_BLKS) {
        int o = (b - CONV_BLKS) * 256 + t;        // 655360 total
        int mat = o >> 16, idx = o & 65535;
        int n = idx >> 8, k = idx & 255;
        wdst[o] = f2b(wsrc.p[mat][k * 256 + n]);
    } else {
        int i = (b - CONV_BLKS - TRW_BLKS) * 256 + t;
        if (i < NTOT) cnt[i] = 0;
    }
}

// ---------------- CSR build ----------------

// histogram + per-edge rank in one pass (atomic return IS the rank)
__global__ void rank_kernel(const int* __restrict__ src, const int* __restrict__ dst,
                            int* cnt_drug, int* cnt_dis,
                            unsigned short* __restrict__ rank_sd,
                            unsigned short* __restrict__ rank_ds, int n) {
    int i = blockIdx.x * blockDim.x + threadIdx.x;
    if (i < n) {
        int s = src[i], d = dst[i];
        rank_ds[i] = (unsigned short)atomicAdd(&cnt_dis[d], 1);
        rank_sd[i] = (unsigned short)atomicAdd(&cnt_drug[s], 1);
    }
}

// hierarchical scan over concatenated [cnt_dis | cnt_drug] (NTOT ints)
__global__ __launch_bounds__(256) void scan_part(const int* __restrict__ cnt,
                                                 int* __restrict__ bsum) {
    __shared__ int red[4];
    int t = threadIdx.x, lane = t & 63, wid = t >> 6;
    int base = blockIdx.x * 1024 + t * 4;
    int s = 0;
    if (base < NTOT) {           // NTOT % 4 == 0 -> whole int4 in bounds
        int4 c = *reinterpret_cast<const int4*>(cnt + base);
        s = c.x + c.y + c.z + c.w;
    }
#pragma unroll
    for (int off = 32; off; off >>= 1) s += __shfl_down(s, off);
    if (lane == 0) red[wid] = s;
    __syncthreads();
    if (t == 0) bsum[blockIdx.x] = red[0] + red[1] + red[2] + red[3];
}

__global__ void scan_top(int* bsum, int nb) {   // 1 block x 64 threads, nb <= 128
    int lane = threadIdx.x;
    int a0 = lane < nb ? bsum[lane] : 0;
    int a1 = (64 + lane) < nb ? bsum[64 + lane] : 0;
    int i0 = a0, i1 = a1;
#pragma unroll
    for (int off = 1; off < 64; off <<= 1) {
        int t0 = __shfl_up(i0, off);
        int t1 = __shfl_up(i1, off);
        if (lane >= off) { i0 += t0; i1 += t1; }
    }
    int tot0 = __shfl(i0, 63);
    if (lane < nb) bsum[lane] = i0 - a0;                    // exclusive
    if (64 + lane < nb) bsum[64 + lane] = tot0 + i1 - a1;
}

__global__ __launch_bounds__(256) void scan_emit(const int* __restrict__ cnt,
                                                 const int* __restrict__ boff,
                                                 int* __restrict__ row_dis,
                                                 int* __restrict__ row_drug,
                                                 float* __restrict__ inv_dis,
                                                 float* __restrict__ inv_drug) {
    __shared__ int wsum[4];
    int t = threadIdx.x, lane = t & 63, wid = t >> 6;
    int base = blockIdx.x * 1024 + t * 4;
    int4 c = make_int4(0, 0, 0, 0);
    if (base < NTOT) c = *reinterpret_cast<const int4*>(cnt + base);
    int sl = c.x + c.y + c.z + c.w;
    int sc = sl;
#pragma unroll
    for (int off = 1; off < 64; off <<= 1) {
        int tv = __shfl_up(sc, off);
        if (lane >= off) sc += tv;
    }
    if (lane == 63) wsum[wid] = sc;
    __syncthreads();
    int woff = 0;
    for (int w2 = 0; w2 < wid; ++w2) woff += wsum[w2];
    int run = boff[blockIdx.x] + woff + (sc - sl);   // exclusive prefix of this thread's 1st elem
    int cc[4] = { c.x, c.y, c.z, c.w };
    if (base < NTOT) {
#pragma unroll
        for (int k = 0; k < 4; ++k) {
            int i = base + k;
            float iv = 1.0f / (float)(cc[k] > 1 ? cc[k] : 1);
            if (i < NS) { row_dis[i] = run; inv_dis[i] = iv; }
            else        { row_drug[i - NS] = run - NE; inv_drug[i - NS] = iv; }
            run += cc[k];
        }
    }
    if (blockIdx.x == 0 && t == 0) { row_dis[NS] = NE; row_drug[ND] = NE; }
}

// place edges: plain stores, no atomic dependency; u16 payload
__global__ void place_kernel(const int* __restrict__ src, const int* __restrict__ dst,
                             const int* __restrict__ row_drug, const int* __restrict__ row_dis,
                             const unsigned short* __restrict__ rank_sd,
                             const unsigned short* __restrict__ rank_ds,
                             unsigned short* __restrict__ val_sd,
                             unsigned short* __restrict__ val_ds, int n) {
    int i = blockIdx.x * blockDim.x + threadIdx.x;
    if (i < n) {
        int s = src[i], d = dst[i];
        val_ds[row_dis[d] + (int)rank_ds[i]] = (unsigned short)s;
        val_sd[row_drug[s] + (int)rank_sd[i]] = (unsigned short)d;
    }
}

// ---------------- fused mean aggregation, 2 rows/wave-load, 8 loads/lane in flight ----------------
// wave per node; lanes 0-31 row j, lanes 32-63 row j+1; 8-pair unroll = 16 edges/iter,
// 8 outstanding 16-B loads per lane (16 x 512-B row gathers in flight per wave).

__global__ __launch_bounds__(256) void agg_bf2(const unsigned short* __restrict__ srcDis,
                                               const unsigned short* __restrict__ srcDrug,
                                               const int* __restrict__ row_dis,
                                               const int* __restrict__ row_drug,
                                               const unsigned short* __restrict__ val_ds,
                                               const unsigned short* __restrict__ val_sd,
                                               const float* __restrict__ inv_dis,
                                               const float* __restrict__ inv_drug,
                                               unsigned short* __restrict__ outDis,
                                               unsigned short* __restrict__ outDrug) {
    int wid = threadIdx.x >> 6, lane = threadIdx.x & 63;
    int node = blockIdx.x * 4 + wid;
    const int half = lane >> 5;          // 0: row j, 1: row j+1
    const int sub = lane & 31;           // feature chunk [sub*8, sub*8+8)
    const unsigned short* xsrc; const int* row; const unsigned short* vals;
    const float* inv; unsigned short* outp;
    if (node < NS) {
        xsrc = srcDis; row = row_dis; vals = val_ds; inv = inv_dis; outp = outDis;
    } else {
        node -= NS;
        if (node >= ND) return;
        xsrc = srcDrug; row = row_drug; vals = val_sd; inv = inv_drug; outp = outDrug;
    }
    const int beg = row[node], end = row[node + 1];
    const int off = sub * 8;
    float a[8] = {};
    int j = beg;
    // 8 pairs = 16 rows in flight per wave (8 loads/lane)
    for (; j + 16 <= end; j += 16) {
        int rr[8];
#pragma unroll
        for (int k = 0; k < 8; ++k) rr[k] = vals[j + 2 * k + half];
        short8 v[8];
#pragma unroll
        for (int k = 0; k < 8; ++k)
            v[k] = *reinterpret_cast<const short8*>(xsrc + rr[k] * 256 + off);
#pragma unroll
        for (int k = 0; k < 8; ++k)
#pragma unroll
            for (int q = 0; q < 8; ++q)
                a[q] += b2f((unsigned short)v[k][q]);
    }
    for (; j + 8 <= end; j += 8) {
        int r0 = vals[j     + half];
        int r1 = vals[j + 2 + half];
        int r2 = vals[j + 4 + half];
        int r3 = vals[j + 6 + half];
        short8 v0 = *reinterpret_cast<const short8*>(xsrc + r0 * 256 + off);
        short8 v1 = *reinterpret_cast<const short8*>(xsrc + r1 * 256 + off);
        short8 v2 = *reinterpret_cast<const short8*>(xsrc + r2 * 256 + off);
        short8 v3 = *reinterpret_cast<const short8*>(xsrc + r3 * 256 + off);
#pragma unroll
        for (int k = 0; k < 8; ++k)
            a[k] += b2f((unsigned short)v0[k]) + b2f((unsigned short)v1[k])
                  + b2f((unsigned short)v2[k]) + b2f((unsigned short)v3[k]);
    }
    for (; j + 2 <= end; j += 2) {
        int r = vals[j + half];
        short8 v = *reinterpret_cast<const short8*>(xsrc + r * 256 + off);
#pragma unroll
        for (int k = 0; k < 8; ++k) a[k] += b2f((unsigned short)v[k]);
    }
    if (j < end && half == 0) {          // odd tail: lanes 0-31 only
        int r = vals[j];
        short8 v = *reinterpret_cast<const short8*>(xsrc + r * 256 + off);
#pragma unroll
        for (int k = 0; k < 8; ++k) a[k] += b2f((unsigned short)v[k]);
    }
#pragma unroll
    for (int k = 0; k < 8; ++k) a[k] += __shfl_xor(a[k], 32);
    if (half == 0) {
        const float iv = inv[node];
        short8 o;
#pragma unroll
        for (int k = 0; k < 8; ++k) o[k] = (short)f2b(a[k] * iv);
        *reinterpret_cast<short8*>(outp + node * 256 + off) = o;
    }
}

// ---------------- LDS-staged bf16 MFMA GEMM (r7 single-buffer, proven best) ----------------
// Per segment: C[M,256] = act( A1@B1 (+ A2@B2) + bias ). Tile 128(M)x128(N), BK=64,
// 4 waves 2x2. 32 KB LDS -> 4 blocks/CU; cross-block overlap hides barrier drains.
// XOR swizzle slot^=(row&7) on GLOBAL SOURCE (LDS dest linear, rule #21), same XOR
// on ds_read -> conflict-free.

struct GemmSeg {
    const unsigned short* A1;
    const unsigned short* A2;
    const unsigned short* B1t;
    const unsigned short* B2t;
    const float* bias;
    unsigned short* C;
    int M; int relu; int nblk; int nsteps;   // nsteps: 8 = two passes, 4 = one pass
};

__global__ __launch_bounds__(256) void gemm_lds(GemmSeg sa, GemmSeg sb) {
    __shared__ unsigned short As[128 * 64];
    __shared__ unsigned short Bs[128 * 64];
    GemmSeg s;
    int bx = blockIdx.x;
    if (bx < sa.nblk) s = sa;
    else { s = sb; bx -= sa.nblk; }

    const int t = threadIdx.x;
    const int lane = t & 63, w = t >> 6;
    const int wr = w >> 1, wc = w & 1;
    const int fr = lane & 15, g = lane >> 4;
    const int bm0 = bx * 128;
    const int n0b = (int)blockIdx.y * 128;
    const int M = s.M;
    const int r8 = lane >> 3, slotL = lane & 7;   // staging: 8 lanes/row, 16B slots

    f32x4 acc[4][4];
#pragma unroll
    for (int m = 0; m < 4; ++m)
#pragma unroll
        for (int n = 0; n < 4; ++n)
            acc[m][n] = (f32x4){0.f, 0.f, 0.f, 0.f};

    for (int st = 0; st < s.nsteps; ++st) {
        const int k0 = (st & 3) * 64;
        const unsigned short* Ap = (st & 4) ? s.A2 : s.A1;
        const unsigned short* Bp = (st & 4) ? s.B2t : s.B1t;
#pragma unroll
        for (int j = 0; j < 4; ++j) {
            const int is = w * 4 + j;             // issue 0..15
            const int row = is * 8 + r8;          // LDS row 0..127
            const int sl = slotL ^ (row & 7);     // inverse-swizzled source slot
            int ra = bm0 + row; if (ra >= M) ra = M - 1;
            gload_lds16(Ap + (size_t)ra * 256 + k0 + sl * 8, &As[is * 512]);
            gload_lds16(Bp + (size_t)(n0b + row) * 256 + k0 + sl * 8, &Bs[is * 512]);
        }
        __syncthreads();   // compiler emits vmcnt(0) drain before barrier
#pragma unroll
        for (int kc = 0; kc < 2; ++kc) {
            const int q = kc * 4 + g;             // logical 16B k-slot
            short8 a[4], b[4];
#pragma unroll
            for (int n = 0; n < 4; ++n) {
                const int br = wc * 64 + n * 16 + fr;
                b[n] = *reinterpret_cast<const short8*>(&Bs[br * 64 + (q ^ (fr & 7)) * 8]);
            }
#pragma unroll
            for (int m = 0; m < 4; ++m) {
                const int ar = wr * 64 + m * 16 + fr;
                a[m] = *reinterpret_cast<const short8*>(&As[ar * 64 + (q ^ (fr & 7)) * 8]);
            }
#pragma unroll
            for (int m = 0; m < 4; ++m)
#pragma unroll
                for (int n = 0; n < 4; ++n)
                    acc[m][n] = __builtin_amdgcn_mfma_f32_16x16x32_bf16(a[m], b[n], acc[m][n], 0, 0, 0);
        }
        __syncthreads();   // WAR: all reads done before next stage overwrites
    }

    // epilogue: D row = base + g*4 + r, col = base + fr  [verified m89/m91]
#pragma unroll
    for (int n = 0; n < 4; ++n) {
        const int col = n0b + wc * 64 + n * 16 + fr;
        const float bv = s.bias ? s.bias[col] : 0.0f;
#pragma unroll
        for (int m = 0; m < 4; ++m) {
#pragma unroll
            for (int r = 0; r < 4; ++r) {
                int row = bm0 + wr * 64 + m * 16 + g * 4 + r;
                if (row < M) {
                    float v = acc[m][n][r] + bv;
                    if (s.relu) v = fmaxf(v, 0.f);
                    s.C[row * 256 + col] = f2b(v);
                }
            }
        }
    }
}

// ---------------- edge decoder: out[e] = relu(Pd[r]+Ps[c]+b1) . w2 + b2 ----------------

__global__ __launch_bounds__(256) void dec_edge(const unsigned short* __restrict__ Pd,
                                                const unsigned short* __restrict__ Ps,
                                                const int* __restrict__ lrow,
                                                const int* __restrict__ lcol,
                                                const float* __restrict__ b1,
                                                const float* __restrict__ w2,
                                                const float* __restrict__ b2,
                                                float* __restrict__ outp, int n) {
    int wid = threadIdx.x >> 6, lane = threadIdx.x & 63;
    int e = blockIdx.x * 4 + wid;
    if (e >= n) return;
    int r = lrow[e], c = lcol[e];
    const int off = lane * 4;
    ushort4 pd = *reinterpret_cast<const ushort4*>(Pd + r * 256 + off);
    ushort4 ps = *reinterpret_cast<const ushort4*>(Ps + c * 256 + off);
    float4 bb = *reinterpret_cast<const float4*>(b1 + off);
    float4 ww = *reinterpret_cast<const float4*>(w2 + off);
    float s = 0.f;
    s += fmaxf(b2f(pd.x) + b2f(ps.x) + bb.x, 0.f) * ww.x;
    s += fmaxf(b2f(pd.y) + b2f(ps.y) + bb.y, 0.f) * ww.y;
    s += fmaxf(b2f(pd.z) + b2f(ps.z) + bb.z, 0.f) * ww.z;
    s += fmaxf(b2f(pd.w) + b2f(ps.w) + bb.w, 0.f) * ww.w;
#pragma unroll
    for (int o = 32; o; o >>= 1) s += __shfl_down(s, o);
    if (lane == 0) outp[e] = s + b2[0];
}

// ---------------- launch ----------------

extern "C" void kernel_launch(void* const* d_in, const int* in_sizes, int n_in,
                              void* d_out, int out_size, void* d_ws, size_t ws_size,
                              hipStream_t stream) {
    const float* x_drug = (const float*)d_in[0];
    const float* x_dis  = (const float*)d_in[1];
    const int* esrc = (const int*)d_in[2];
    const int* edst = (const int*)d_in[3];
    const int* lrow = (const int*)d_in[4];
    const int* lcol = (const int*)d_in[5];
    const float* Wl1_ds = (const float*)d_in[6];
    const float* bl1_ds = (const float*)d_in[7];
    const float* Wr1_ds = (const float*)d_in[8];
    const float* Wl1_sd = (const float*)d_in[9];
    const float* bl1_sd = (const float*)d_in[10];
    const float* Wr1_sd = (const float*)d_in[11];
    const float* Wl2_ds = (const float*)d_in[12];
    const float* bl2_ds = (const float*)d_in[13];
    const float* Wr2_ds = (const float*)d_in[14];
    const float* Wl2_sd = (const float*)d_in[15];
    const float* bl2_sd = (const float*)d_in[16];
    const float* Wr2_sd = (const float*)d_in[17];
    const float* Wdec1 = (const float*)d_in[18];
    const float* bdec1 = (const float*)d_in[19];
    const float* Wdec2 = (const float*)d_in[20];
    const float* bdec2 = (const float*)d_in[21];
    float* outp = (float*)d_out;

    char* ws = (char*)d_ws;
    size_t off = 0;
    auto alloc = [&](size_t bytes) -> void* {
        void* p = ws + off;
        off = (off + bytes + 255) & ~(size_t)255;
        return p;
    };
    int* cnt       = (int*)alloc((size_t)NTOT * 4);      // [cnt_dis | cnt_drug]
    int* bsum      = (int*)alloc((size_t)SCAN_BLK * 4);
    int* row_dis   = (int*)alloc((size_t)(NS + 1) * 4);
    int* row_drug  = (int*)alloc((size_t)(ND + 1) * 4);
    float* inv_dis = (float*)alloc((size_t)NS * 4);
    float* inv_drug= (float*)alloc((size_t)ND * 4);
    unsigned short* rank_ds = (unsigned short*)alloc((size_t)NE * 2);
    unsigned short* rank_sd = (unsigned short*)alloc((size_t)NE * 2);
    unsigned short* val_ds  = (unsigned short*)alloc((size_t)NE * 2);
    unsigned short* val_sd  = (unsigned short*)alloc((size_t)NE * 2);
    unsigned short* Wt   = (unsigned short*)alloc((size_t)10 * 65536 * 2);
    unsigned short* xd_b = (unsigned short*)alloc((size_t)ND * 256 * 2);
    unsigned short* xs_b = (unsigned short*)alloc((size_t)NS * 256 * 2);
    unsigned short* aggs = (unsigned short*)alloc((size_t)NS * 256 * 2);  // dis-dst agg
    unsigned short* aggd = (unsigned short*)alloc((size_t)ND * 256 * 2);  // drug-dst agg
    unsigned short* zd1  = (unsigned short*)alloc((size_t)ND * 256 * 2);
    unsigned short* zs1  = (unsigned short*)alloc((size_t)NS * 256 * 2);
    unsigned short* zd2  = (unsigned short*)alloc((size_t)ND * 256 * 2);
    unsigned short* zs2  = (unsigned short*)alloc((size_t)NS * 256 * 2);
    unsigned short* Pd   = (unsigned short*)alloc((size_t)ND * 256 * 2);
    unsigned short* Ps   = (unsigned short*)alloc((size_t)NS * 256 * 2);
    int* cnt_dis = cnt;
    int* cnt_drug = cnt + NS;

    // --- fused prep: x->bf16, W->bf16^T, zero counters ---
    W10 wsrc;
    wsrc.p[0] = Wl1_ds; wsrc.p[1] = Wr1_ds; wsrc.p[2] = Wl1_sd; wsrc.p[3] = Wr1_sd;
    wsrc.p[4] = Wl2_ds; wsrc.p[5] = Wr2_ds; wsrc.p[6] = Wl2_sd; wsrc.p[7] = Wr2_sd;
    wsrc.p[8] = Wdec1;                 // rows 0..255  (zd part)
    wsrc.p[9] = Wdec1 + 256 * 256;     // rows 256..511 (zs part)
    prep_kernel<<<CONV_BLKS + TRW_BLKS + ZERO_BLKS, 256, 0, stream>>>(
        x_drug, x_dis, xd_b, xs_b, wsrc, Wt, cnt);
    unsigned short* WT[10];
    for (int i = 0; i < 10; ++i) WT[i] = Wt + (size_t)i * 65536;

    // --- CSR build ---
    rank_kernel<<<(NE + 255) / 256, 256, 0, stream>>>(esrc, edst, cnt_drug, cnt_dis,
                                                      rank_sd, rank_ds, NE);
    scan_part<<<SCAN_BLK, 256, 0, stream>>>(cnt, bsum);
    scan_top<<<1, 64, 0, stream>>>(bsum, SCAN_BLK);
    scan_emit<<<SCAN_BLK, 256, 0, stream>>>(cnt, bsum, row_dis, row_drug, inv_dis, inv_drug);
    place_kernel<<<(NE + 255) / 256, 256, 0, stream>>>(esrc, edst, row_drug, row_dis,
                                                       rank_sd, rank_ds, val_sd, val_ds, NE);

    const int AGG_GRID = (NTOT + 3) / 4;
    const int NB_NS = (NS + 127) / 128, NB_ND = (ND + 127) / 128;
    dim3 gemm_grid(NB_NS + NB_ND, 2);

    // --- layer 1 (relu) ---
    agg_bf2<<<AGG_GRID, 256, 0, stream>>>(xd_b, xs_b, row_dis, row_drug, val_ds, val_sd,
                                          inv_dis, inv_drug, aggs, aggd);
    {
        GemmSeg a = { aggs, xs_b, WT[0], WT[1], bl1_ds, zs1, NS, 1, NB_NS, 8 };
        GemmSeg b = { aggd, xd_b, WT[2], WT[3], bl1_sd, zd1, ND, 1, NB_ND, 8 };
        gemm_lds<<<gemm_grid, 256, 0, stream>>>(a, b);
    }

    // --- layer 2 (no relu) ---
    agg_bf2<<<AGG_GRID, 256, 0, stream>>>(zd1, zs1, row_dis, row_drug, val_ds, val_sd,
                                          inv_dis, inv_drug, aggs, aggd);
    {
        GemmSeg a = { aggs, zs1, WT[4], WT[5], bl2_ds, zs2, NS, 0, NB_NS, 8 };
        GemmSeg b = { aggd, zd1, WT[6], WT[7], bl2_sd, zd2, ND, 0, NB_ND, 8 };
        gemm_lds<<<gemm_grid, 256, 0, stream>>>(a, b);
    }

    // --- decoder projections (fused, single pass) ---
    {
        GemmSeg a = { zd2, nullptr, WT[8], nullptr, nullptr, Pd, ND, 0, NB_ND, 4 };
        GemmSeg b = { zs2, nullptr, WT[9], nullptr, nullptr, Ps, NS, 0, NB_NS, 4 };
        gemm_lds<<<gemm_grid, 256, 0, stream>>>(a, b);
    }
    dec_edge<<<(EL + 3) / 4, 256, 0, stream>>>(Pd, Ps, lrow, lcol, bdec1, Wdec2, bdec2, outp, EL);
}

// Round 11
// 532.397 us; speedup vs baseline: 2.3068x; 1.0700x over previous
//
#include <hip/hip_runtime.h>
#include <hip/hip_bf16.h>

#define ND 50000
#define NS 30000
#define NE 1000000
#define EL 200000
#define NTOT (NS + ND)          // 80000
#define SCAN_BLK ((NTOT + 1023) / 1024)   // 79

#define RANK_BLKS ((NE + 255) / 256)      // 3907
#define CONV_BLKS 20000                   // (ND+NS)*256/1024 exact
#define TRW4_BLKS 1024                    // 4 mats * 65536 / 256
#define COMP_BLKS 64                      // 4 mats * 16 k-tiles
#define BIAS_BLKS 2
#define MEGA_BLKS (RANK_BLKS + CONV_BLKS + TRW4_BLKS + COMP_BLKS + BIAS_BLKS)

typedef short short8 __attribute__((ext_vector_type(8)));
typedef float f32x4 __attribute__((ext_vector_type(4)));

__device__ __forceinline__ float b2f(unsigned short u) {
    union { unsigned int i; float f; } c; c.i = ((unsigned int)u) << 16; return c.f;
}
__device__ __forceinline__ unsigned short f2b(float f) {
    __hip_bfloat16 h = __float2bfloat16(f);   // RNE
    union { __hip_bfloat16 h; unsigned short u; } c; c.h = h; return c.u;
}

// async global->LDS, 16 B per lane; LDS dest is wave-uniform base + lane*16
__device__ __forceinline__ void gload_lds16(const unsigned short* g, unsigned short* l) {
    __builtin_amdgcn_global_load_lds(
        (const __attribute__((address_space(1))) unsigned int*)g,
        (__attribute__((address_space(3))) unsigned int*)l, 16, 0, 0);
}

struct WAll {
    const float* w1[4];      // Wl1_ds, Wr1_ds, Wl1_sd, Wr1_sd  -> WT[0..3] (plain transpose)
    const float* w2[4];      // Wl2_ds, Wr2_ds, Wl2_sd, Wr2_sd  -> WT[4..7] (composed with Wdec1 halves)
    const float* wdec1;      // [512][256]; rows 0..255 = Wtop (zd), 256..511 = Wbot (zs)
    const float* bl2_ds;
    const float* bl2_sd;
};

__global__ void zero_kernel(int* a, int n) {
    int i = blockIdx.x * blockDim.x + threadIdx.x;
    if (i < n) a[i] = 0;
}

// ---------------- mega prep: rank (atomic) co-runs with conv/transpose/compose (BW) ----------------
// Decoder fold: layer 2 is linear (no relu), so
//   Ps = aggs@(Wl2_ds@Wbot) + zs1@(Wr2_ds@Wbot) + bl2_ds@Wbot
//   Pd = aggd@(Wl2_sd@Wtop) + zd1@(Wr2_sd@Wtop) + bl2_sd@Wtop
// Composed 256x256 products computed here in fp32, stored bf16 transposed.
__global__ __launch_bounds__(256) void mega_prep(const int* __restrict__ esrc,
                                                 const int* __restrict__ edst,
                                                 int* cnt_drug, int* cnt_dis,
                                                 unsigned short* __restrict__ rank_sd,
                                                 unsigned short* __restrict__ rank_ds,
                                                 const float* __restrict__ xd,
                                                 const float* __restrict__ xs,
                                                 unsigned short* __restrict__ xd_b,
                                                 unsigned short* __restrict__ xs_b,
                                                 WAll wa,
                                                 unsigned short* __restrict__ Wt,
                                                 float* __restrict__ cbuf) {
    __shared__ float w2t[16][256];
    const int b = blockIdx.x, t = threadIdx.x;
    if (b < RANK_BLKS) {
        // histogram + per-edge rank (atomic return IS the rank)
        int i = b * 256 + t;
        if (i < NE) {
            int s = esrc[i], d = edst[i];
            rank_ds[i] = (unsigned short)atomicAdd(&cnt_dis[d], 1);
            rank_sd[i] = (unsigned short)atomicAdd(&cnt_drug[s], 1);
        }
    } else if (b < RANK_BLKS + CONV_BLKS) {
        // x fp32 -> bf16
        int i = ((b - RANK_BLKS) * 256 + t) * 4;
        const int NDE = ND * 256;
        if (i < NDE) {
            float4 v = *reinterpret_cast<const float4*>(xd + i);
            ushort4 o; o.x = f2b(v.x); o.y = f2b(v.y); o.z = f2b(v.z); o.w = f2b(v.w);
            *reinterpret_cast<ushort4*>(xd_b + i) = o;
        } else {
            int j = i - NDE;
            float4 v = *reinterpret_cast<const float4*>(xs + j);
            ushort4 o; o.x = f2b(v.x); o.y = f2b(v.y); o.z = f2b(v.z); o.w = f2b(v.w);
            *reinterpret_cast<ushort4*>(xs_b + j) = o;
        }
    } else if (b < RANK_BLKS + CONV_BLKS + TRW4_BLKS) {
        // layer-1 weights: plain transpose to bf16 [n][k]
        int o = (b - RANK_BLKS - CONV_BLKS) * 256 + t;    // 262144
        int mat = o >> 16, idx = o & 65535;
        int n = idx >> 8, k = idx & 255;
        Wt[o] = f2b(wa.w1[mat][k * 256 + n]);
    } else if (b < RANK_BLKS + CONV_BLKS + TRW4_BLKS + COMP_BLKS) {
        // composed weights: CT[n][k] = sum_j W2[k][j] * Wd[j][n], fp32 accum -> bf16
        int cb = b - RANK_BLKS - CONV_BLKS - TRW4_BLKS;   // 0..63
        int mat = cb >> 4;
        int k0 = (cb & 15) * 16;
        const float* W2 = wa.w2[mat];
        const float* Wd = wa.wdec1 + ((mat < 2) ? 65536 : 0);   // ds->Wbot, sd->Wtop
        for (int idx = t; idx < 4096; idx += 256) {
            int r = idx >> 8, c = idx & 255;
            w2t[r][c] = W2[(k0 + r) * 256 + c];
        }
        __syncthreads();
        float acc[16] = {};
        const int n = t;
        for (int j = 0; j < 256; ++j) {
            float wd = Wd[j * 256 + n];
#pragma unroll
            for (int k = 0; k < 16; ++k) acc[k] += w2t[k][j] * wd;
        }
        unsigned short* dst = Wt + (size_t)(4 + mat) * 65536 + n * 256 + k0;
#pragma unroll
        for (int k = 0; k < 16; ++k) dst[k] = f2b(acc[k]);
    } else {
        // composed biases: cbuf[0][n] = bl2_ds@Wbot, cbuf[1][n] = bl2_sd@Wtop
        int bb = b - RANK_BLKS - CONV_BLKS - TRW4_BLKS - COMP_BLKS;   // 0 or 1
        const float* bsrc = bb ? wa.bl2_sd : wa.bl2_ds;
        const float* Wd = wa.wdec1 + (bb ? 0 : 65536);
        float acc = 0.f;
        const int n = t;
        for (int j = 0; j < 256; ++j) acc += bsrc[j] * Wd[j * 256 + n];
        cbuf[bb * 256 + n] = acc;
    }
}

// ---------------- scan ----------------

__global__ __launch_bounds__(256) void scan_part(const int* __restrict__ cnt,
                                                 int* __restrict__ bsum) {
    __shared__ int red[4];
    int t = threadIdx.x, lane = t & 63, wid = t >> 6;
    int base = blockIdx.x * 1024 + t * 4;
    int s = 0;
    if (base < NTOT) {
        int4 c = *reinterpret_cast<const int4*>(cnt + base);
        s = c.x + c.y + c.z + c.w;
    }
#pragma unroll
    for (int off = 32; off; off >>= 1) s += __shfl_down(s, off);
    if (lane == 0) red[wid] = s;
    __syncthreads();
    if (t == 0) bsum[blockIdx.x] = red[0] + red[1] + red[2] + red[3];
}

__global__ void scan_top(int* bsum, int nb) {
    int lane = threadIdx.x;
    int a0 = lane < nb ? bsum[lane] : 0;
    int a1 = (64 + lane) < nb ? bsum[64 + lane] : 0;
    int i0 = a0, i1 = a1;
#pragma unroll
    for (int off = 1; off < 64; off <<= 1) {
        int t0 = __shfl_up(i0, off);
        int t1 = __shfl_up(i1, off);
        if (lane >= off) { i0 += t0; i1 += t1; }
    }
    int tot0 = __shfl(i0, 63);
    if (lane < nb) bsum[lane] = i0 - a0;
    if (64 + lane < nb) bsum[64 + lane] = tot0 + i1 - a1;
}

__global__ __launch_bounds__(256) void scan_emit(const int* __restrict__ cnt,
                                                 const int* __restrict__ boff,
                                                 int* __restrict__ row_dis,
                                                 int* __restrict__ row_drug,
                                                 float* __restrict__ inv_dis,
                                                 float* __restrict__ inv_drug) {
    __shared__ int wsum[4];
    int t = threadIdx.x, lane = t & 63, wid = t >> 6;
    int base = blockIdx.x * 1024 + t * 4;
    int4 c = make_int4(0, 0, 0, 0);
    if (base < NTOT) c = *reinterpret_cast<const int4*>(cnt + base);
    int sl = c.x + c.y + c.z + c.w;
    int sc = sl;
#pragma unroll
    for (int off = 1; off < 64; off <<= 1) {
        int tv = __shfl_up(sc, off);
        if (lane >= off) sc += tv;
    }
    if (lane == 63) wsum[wid] = sc;
    __syncthreads();
    int woff = 0;
    for (int w2 = 0; w2 < wid; ++w2) woff += wsum[w2];
    int run = boff[blockIdx.x] + woff + (sc - sl);
    int cc[4] = { c.x, c.y, c.z, c.w };
    if (base < NTOT) {
#pragma unroll
        for (int k = 0; k < 4; ++k) {
            int i = base + k;
            float iv = 1.0f / (float)(cc[k] > 1 ? cc[k] : 1);
            if (i < NS) { row_dis[i] = run; inv_dis[i] = iv; }
            else        { row_drug[i - NS] = run - NE; inv_drug[i - NS] = iv; }
            run += cc[k];
        }
    }
    if (blockIdx.x == 0 && t == 0) { row_dis[NS] = NE; row_drug[ND] = NE; }
}

// place edges: plain stores, no atomic dependency; u16 payload
__global__ void place_kernel(const int* __restrict__ src, const int* __restrict__ dst,
                             const int* __restrict__ row_drug, const int* __restrict__ row_dis,
                             const unsigned short* __restrict__ rank_sd,
                             const unsigned short* __restrict__ rank_ds,
                             unsigned short* __restrict__ val_sd,
                             unsigned short* __restrict__ val_ds, int n) {
    int i = blockIdx.x * blockDim.x + threadIdx.x;
    if (i < n) {
        int s = src[i], d = dst[i];
        val_ds[row_dis[d] + (int)rank_ds[i]] = (unsigned short)s;
        val_sd[row_drug[s] + (int)rank_sd[i]] = (unsigned short)d;
    }
}

// ---------------- fused mean aggregation (r10 shape, at its measured floor) ----------------

__global__ __launch_bounds__(256) void agg_bf2(const unsigned short* __restrict__ srcDis,
                                               const unsigned short* __restrict__ srcDrug,
                                               const int* __restrict__ row_dis,
                                               const int* __restrict__ row_drug,
                                               const unsigned short* __restrict__ val_ds,
                                               const unsigned short* __restrict__ val_sd,
                                               const float* __restrict__ inv_dis,
                                               const float* __restrict__ inv_drug,
                                               unsigned short* __restrict__ outDis,
                                               unsigned short* __restrict__ outDrug) {
    int wid = threadIdx.x >> 6, lane = threadIdx.x & 63;
    int node = blockIdx.x * 4 + wid;
    const int half = lane >> 5;
    const int sub = lane & 31;
    const unsigned short* xsrc; const int* row; const unsigned short* vals;
    const float* inv; unsigned short* outp;
    if (node < NS) {
        xsrc = srcDis; row = row_dis; vals = val_ds; inv = inv_dis; outp = outDis;
    } else {
        node -= NS;
        if (node >= ND) return;
        xsrc = srcDrug; row = row_drug; vals = val_sd; inv = inv_drug; outp = outDrug;
    }
    const int beg = row[node], end = row[node + 1];
    const int off = sub * 8;
    float a[8] = {};
    int j = beg;
    for (; j + 8 <= end; j += 8) {
        int r0 = vals[j     + half];
        int r1 = vals[j + 2 + half];
        int r2 = vals[j + 4 + half];
        int r3 = vals[j + 6 + half];
        short8 v0 = *reinterpret_cast<const short8*>(xsrc + r0 * 256 + off);
        short8 v1 = *reinterpret_cast<const short8*>(xsrc + r1 * 256 + off);
        short8 v2 = *reinterpret_cast<const short8*>(xsrc + r2 * 256 + off);
        short8 v3 = *reinterpret_cast<const short8*>(xsrc + r3 * 256 + off);
#pragma unroll
        for (int k = 0; k < 8; ++k)
            a[k] += b2f((unsigned short)v0[k]) + b2f((unsigned short)v1[k])
                  + b2f((unsigned short)v2[k]) + b2f((unsigned short)v3[k]);
    }
    for (; j + 2 <= end; j += 2) {
        int r = vals[j + half];
        short8 v = *reinterpret_cast<const short8*>(xsrc + r * 256 + off);
#pragma unroll
        for (int k = 0; k < 8; ++k) a[k] += b2f((unsigned short)v[k]);
    }
    if (j < end && half == 0) {
        int r = vals[j];
        short8 v = *reinterpret_cast<const short8*>(xsrc + r * 256 + off);
#pragma unroll
        for (int k = 0; k < 8; ++k) a[k] += b2f((unsigned short)v[k]);
    }
#pragma unroll
    for (int k = 0; k < 8; ++k) a[k] += __shfl_xor(a[k], 32);
    if (half == 0) {
        const float iv = inv[node];
        short8 o;
#pragma unroll
        for (int k = 0; k < 8; ++k) o[k] = (short)f2b(a[k] * iv);
        *reinterpret_cast<short8*>(outp + node * 256 + off) = o;
    }
}

// ---------------- LDS-staged bf16 MFMA GEMM (r7 single-buffer, proven best) ----------------

struct GemmSeg {
    const unsigned short* A1;
    const unsigned short* A2;
    const unsigned short* B1t;
    const unsigned short* B2t;
    const float* bias;
    unsigned short* C;
    int M; int relu; int nblk; int nsteps;
};

__global__ __launch_bounds__(256) void gemm_lds(GemmSeg sa, GemmSeg sb) {
    __shared__ unsigned short As[128 * 64];
    __shared__ unsigned short Bs[128 * 64];
    GemmSeg s;
    int bx = blockIdx.x;
    if (bx < sa.nblk) s = sa;
    else { s = sb; bx -= sa.nblk; }

    const int t = threadIdx.x;
    const int lane = t & 63, w = t >> 6;
    const int wr = w >> 1, wc = w & 1;
    const int fr = lane & 15, g = lane >> 4;
    const int bm0 = bx * 128;
    const int n0b = (int)blockIdx.y * 128;
    const int M = s.M;
    const int r8 = lane >> 3, slotL = lane & 7;

    f32x4 acc[4][4];
#pragma unroll
    for (int m = 0; m < 4; ++m)
#pragma unroll
        for (int n = 0; n < 4; ++n)
            acc[m][n] = (f32x4){0.f, 0.f, 0.f, 0.f};

    for (int st = 0; st < s.nsteps; ++st) {
        const int k0 = (st & 3) * 64;
        const unsigned short* Ap = (st & 4) ? s.A2 : s.A1;
        const unsigned short* Bp = (st & 4) ? s.B2t : s.B1t;
#pragma unroll
        for (int j = 0; j < 4; ++j) {
            const int is = w * 4 + j;
            const int row = is * 8 + r8;
            const int sl = slotL ^ (row & 7);
            int ra = bm0 + row; if (ra >= M) ra = M - 1;
            gload_lds16(Ap + (size_t)ra * 256 + k0 + sl * 8, &As[is * 512]);
            gload_lds16(Bp + (size_t)(n0b + row) * 256 + k0 + sl * 8, &Bs[is * 512]);
        }
        __syncthreads();
#pragma unroll
        for (int kc = 0; kc < 2; ++kc) {
            const int q = kc * 4 + g;
            short8 a[4], b[4];
#pragma unroll
            for (int n = 0; n < 4; ++n) {
                const int br = wc * 64 + n * 16 + fr;
                b[n] = *reinterpret_cast<const short8*>(&Bs[br * 64 + (q ^ (fr & 7)) * 8]);
            }
#pragma unroll
            for (int m = 0; m < 4; ++m) {
                const int ar = wr * 64 + m * 16 + fr;
                a[m] = *reinterpret_cast<const short8*>(&As[ar * 64 + (q ^ (fr & 7)) * 8]);
            }
#pragma unroll
            for (int m = 0; m < 4; ++m)
#pragma unroll
                for (int n = 0; n < 4; ++n)
                    acc[m][n] = __builtin_amdgcn_mfma_f32_16x16x32_bf16(a[m], b[n], acc[m][n], 0, 0, 0);
        }
        __syncthreads();
    }

#pragma unroll
    for (int n = 0; n < 4; ++n) {
        const int col = n0b + wc * 64 + n * 16 + fr;
        const float bv = s.bias ? s.bias[col] : 0.0f;
#pragma unroll
        for (int m = 0; m < 4; ++m) {
#pragma unroll
            for (int r = 0; r < 4; ++r) {
                int row = bm0 + wr * 64 + m * 16 + g * 4 + r;
                if (row < M) {
                    float v = acc[m][n][r] + bv;
                    if (s.relu) v = fmaxf(v, 0.f);
                    s.C[row * 256 + col] = f2b(v);
                }
            }
        }
    }
}

// ---------------- edge decoder: out[e] = relu(Pd[r]+Ps[c]+b1) . w2 + b2, 2 edges/wave ----------------

__global__ __launch_bounds__(256) void dec_edge(const unsigned short* __restrict__ Pd,
                                                const unsigned short* __restrict__ Ps,
                                                const int* __restrict__ lrow,
                                                const int* __restrict__ lcol,
                                                const float* __restrict__ b1,
                                                const float* __restrict__ w2,
                                                const float* __restrict__ b2,
                                                float* __restrict__ outp, int n) {
    int wid = threadIdx.x >> 6, lane = threadIdx.x & 63;
    int half = lane >> 5, sl = lane & 31;
    int e = blockIdx.x * 8 + wid * 2 + half;
    if (e >= n) return;
    int r = lrow[e], c = lcol[e];
    const int off = sl * 8;
    short8 pd = *reinterpret_cast<const short8*>(Pd + r * 256 + off);
    short8 ps = *reinterpret_cast<const short8*>(Ps + c * 256 + off);
    float s = 0.f;
#pragma unroll
    for (int k = 0; k < 8; ++k) {
        float h = b2f((unsigned short)pd[k]) + b2f((unsigned short)ps[k]) + b1[off + k];
        s += fmaxf(h, 0.f) * w2[off + k];
    }
#pragma unroll
    for (int o = 16; o; o >>= 1) s += __shfl_down(s, o, 32);
    if (sl == 0) outp[e] = s + b2[0];
}

// ---------------- launch ----------------

extern "C" void kernel_launch(void* const* d_in, const int* in_sizes, int n_in,
                              void* d_out, int out_size, void* d_ws, size_t ws_size,
                              hipStream_t stream) {
    const float* x_drug = (const float*)d_in[0];
    const float* x_dis  = (const float*)d_in[1];
    const int* esrc = (const int*)d_in[2];
    const int* edst = (const int*)d_in[3];
    const int* lrow = (const int*)d_in[4];
    const int* lcol = (const int*)d_in[5];
    const float* Wl1_ds = (const float*)d_in[6];
    const float* bl1_ds = (const float*)d_in[7];
    const float* Wr1_ds = (const float*)d_in[8];
    const float* Wl1_sd = (const float*)d_in[9];
    const float* bl1_sd = (const float*)d_in[10];
    const float* Wr1_sd = (const float*)d_in[11];
    const float* Wl2_ds = (const float*)d_in[12];
    const float* bl2_ds = (const float*)d_in[13];
    const float* Wr2_ds = (const float*)d_in[14];
    const float* Wl2_sd = (const float*)d_in[15];
    const float* bl2_sd = (const float*)d_in[16];
    const float* Wr2_sd = (const float*)d_in[17];
    const float* Wdec1 = (const float*)d_in[18];
    const float* bdec1 = (const float*)d_in[19];
    const float* Wdec2 = (const float*)d_in[20];
    const float* bdec2 = (const float*)d_in[21];
    float* outp = (float*)d_out;

    char* ws = (char*)d_ws;
    size_t off = 0;
    auto alloc = [&](size_t bytes) -> void* {
        void* p = ws + off;
        off = (off + bytes + 255) & ~(size_t)255;
        return p;
    };
    int* cnt       = (int*)alloc((size_t)NTOT * 4);      // [cnt_dis | cnt_drug]
    int* bsum      = (int*)alloc((size_t)SCAN_BLK * 4);
    int* row_dis   = (int*)alloc((size_t)(NS + 1) * 4);
    int* row_drug  = (int*)alloc((size_t)(ND + 1) * 4);
    float* inv_dis = (float*)alloc((size_t)NS * 4);
    float* inv_drug= (float*)alloc((size_t)ND * 4);
    float* cbuf    = (float*)alloc((size_t)512 * 4);     // composed biases [cb_s | cb_d]
    unsigned short* rank_ds = (unsigned short*)alloc((size_t)NE * 2);
    unsigned short* rank_sd = (unsigned short*)alloc((size_t)NE * 2);
    unsigned short* val_ds  = (unsigned short*)alloc((size_t)NE * 2);
    unsigned short* val_sd  = (unsigned short*)alloc((size_t)NE * 2);
    unsigned short* Wt   = (unsigned short*)alloc((size_t)8 * 65536 * 2);
    unsigned short* xd_b = (unsigned short*)alloc((size_t)ND * 256 * 2);
    unsigned short* xs_b = (unsigned short*)alloc((size_t)NS * 256 * 2);
    unsigned short* aggs = (unsigned short*)alloc((size_t)NS * 256 * 2);
    unsigned short* aggd = (unsigned short*)alloc((size_t)ND * 256 * 2);
    unsigned short* zd1  = (unsigned short*)alloc((size_t)ND * 256 * 2);
    unsigned short* zs1  = (unsigned short*)alloc((size_t)NS * 256 * 2);
    unsigned short* Pd   = (unsigned short*)alloc((size_t)ND * 256 * 2);
    unsigned short* Ps   = (unsigned short*)alloc((size_t)NS * 256 * 2);
    int* cnt_dis = cnt;
    int* cnt_drug = cnt + NS;

    // --- zero counters (must precede rank atomics) ---
    zero_kernel<<<(NTOT + 255) / 256, 256, 0, stream>>>(cnt, NTOT);

    // --- mega prep: rank atomics co-run with x->bf16, W transpose, W compose ---
    WAll wa;
    wa.w1[0] = Wl1_ds; wa.w1[1] = Wr1_ds; wa.w1[2] = Wl1_sd; wa.w1[3] = Wr1_sd;
    wa.w2[0] = Wl2_ds; wa.w2[1] = Wr2_ds; wa.w2[2] = Wl2_sd; wa.w2[3] = Wr2_sd;
    wa.wdec1 = Wdec1; wa.bl2_ds = bl2_ds; wa.bl2_sd = bl2_sd;
    mega_prep<<<MEGA_BLKS, 256, 0, stream>>>(esrc, edst, cnt_drug, cnt_dis,
                                             rank_sd, rank_ds,
                                             x_drug, x_dis, xd_b, xs_b,
                                             wa, Wt, cbuf);
    unsigned short* WT[8];
    for (int i = 0; i < 8; ++i) WT[i] = Wt + (size_t)i * 65536;

    // --- CSR finish ---
    scan_part<<<SCAN_BLK, 256, 0, stream>>>(cnt, bsum);
    scan_top<<<1, 64, 0, stream>>>(bsum, SCAN_BLK);
    scan_emit<<<SCAN_BLK, 256, 0, stream>>>(cnt, bsum, row_dis, row_drug, inv_dis, inv_drug);
    place_kernel<<<(NE + 255) / 256, 256, 0, stream>>>(esrc, edst, row_drug, row_dis,
                                                       rank_sd, rank_ds, val_sd, val_ds, NE);

    const int AGG_GRID = (NTOT + 3) / 4;
    const int NB_NS = (NS + 127) / 128, NB_ND = (ND + 127) / 128;
    dim3 gemm_grid(NB_NS + NB_ND, 2);

    // --- layer 1 (relu) ---
    agg_bf2<<<AGG_GRID, 256, 0, stream>>>(xd_b, xs_b, row_dis, row_drug, val_ds, val_sd,
                                          inv_dis, inv_drug, aggs, aggd);
    {
        GemmSeg a = { aggs, xs_b, WT[0], WT[1], bl1_ds, zs1, NS, 1, NB_NS, 8 };
        GemmSeg b = { aggd, xd_b, WT[2], WT[3], bl1_sd, zd1, ND, 1, NB_ND, 8 };
        gemm_lds<<<gemm_grid, 256, 0, stream>>>(a, b);
    }

    // --- layer 2 fused with decoder projection (linear fold; writes Ps/Pd directly) ---
    agg_bf2<<<AGG_GRID, 256, 0, stream>>>(zd1, zs1, row_dis, row_drug, val_ds, val_sd,
                                          inv_dis, inv_drug, aggs, aggd);
    {
        GemmSeg a = { aggs, zs1, WT[4], WT[5], cbuf,       Ps, NS, 0, NB_NS, 8 };
        GemmSeg b = { aggd, zd1, WT[6], WT[7], cbuf + 256, Pd, ND, 0, NB_ND, 8 };
        gemm_lds<<<gemm_grid, 256, 0, stream>>>(a, b);
    }

    // --- edge decoder ---
    dec_edge<<<(EL + 7) / 8, 256, 0, stream>>>(Pd, Ps, lrow, lcol, bdec1, Wdec2, bdec2, outp, EL);
}